// Round 2
// baseline (968.760 us; speedup 1.0000x reference)
//
#include <hip/hip_runtime.h>
#include <hip/hip_bf16.h>
#include <stdint.h>

#define DEV static __device__ __forceinline__

typedef __bf16 bf16_t;
typedef __bf16 bf16x8 __attribute__((ext_vector_type(8)));
typedef __bf16 bf16x4 __attribute__((ext_vector_type(4)));
typedef float  f32x4  __attribute__((ext_vector_type(4)));

// H=32 q heads, KV=8 kv heads, D=128, HID=4096, S=4, L=1024, N=4096

DEV void gload_lds16(const void* g, void* l) {
  __builtin_amdgcn_global_load_lds(
      (__attribute__((address_space(1))) void*)(uintptr_t)(g),
      (__attribute__((address_space(3))) void*)(uintptr_t)(l),
      16, 0, 0);
}

#define BARRIER() asm volatile("s_barrier" ::: "memory")
#define MFMA16(a, b, c) __builtin_amdgcn_mfma_f32_16x16x32_bf16((a), (b), (c), 0, 0, 0)

// ---------------- pack/convert kernels ----------------
__global__ void k_pack_pair(const float* __restrict__ A, const float* __restrict__ B,
                            bf16_t* __restrict__ dst, int rows) {
  size_t n4 = (size_t)rows * 1024;
  size_t stride = (size_t)gridDim.x * blockDim.x;
  for (size_t i = (size_t)blockIdx.x * blockDim.x + threadIdx.x; i < n4; i += stride) {
    size_t r = i >> 10, c4 = i & 1023;
    float4 va = ((const float4*)A)[i];
    float4 vb = ((const float4*)B)[i];
    bf16x4 oa = { (bf16_t)va.x, (bf16_t)va.y, (bf16_t)va.z, (bf16_t)va.w };
    bf16x4 ob = { (bf16_t)vb.x, (bf16_t)vb.y, (bf16_t)vb.z, (bf16_t)vb.w };
    ((bf16x4*)dst)[r * 2048 + c4]        = oa;
    ((bf16x4*)dst)[r * 2048 + 1024 + c4] = ob;
  }
}

__global__ void k_convert(const float* __restrict__ A, bf16_t* __restrict__ dst, size_t n4) {
  size_t stride = (size_t)gridDim.x * blockDim.x;
  for (size_t i = (size_t)blockIdx.x * blockDim.x + threadIdx.x; i < n4; i += stride) {
    float4 v = ((const float4*)A)[i];
    bf16x4 o = { (bf16_t)v.x, (bf16_t)v.y, (bf16_t)v.z, (bf16_t)v.w };
    ((bf16x4*)dst)[i] = o;
  }
}

// ---------------- 256x256 8-phase bf16 GEMM: C[M][N] = A[M][K] * B[N][K]^T ----------------
// 512 threads = 8 waves (2M x 4N), BK=64, per-wave C = 128x64 = acc[8][4].
// LDS ring: A[2dbuf][2half][128][64] + B same = 128 KiB. 16B-chunk XOR swizzle (chunk ^= row&7),
// applied on the global SOURCE for global_load_lds (linear dest) and on ds_read addresses.
// Staging order per K-tile: B0,B1,A0,A1; lead 7 half-tiles; vmcnt(6) per tile boundary.
__global__ __launch_bounds__(512, 2) void k_gemm256(
    const bf16_t* __restrict__ A, const bf16_t* __restrict__ B,
    float* __restrict__ C, int M, int N, int K) {
  __shared__ __align__(16) char lds[131072];
  const int tid = threadIdx.x, lane = tid & 63, wid = tid >> 6;
  const int l15 = lane & 15, lhi = lane >> 4;
  const int wr = wid >> 2, wc = wid & 3;
  // bijective XCD swizzle (nwg % 8 == 0 for all our launches)
  const int bid = blockIdx.x, nwg = gridDim.x;
  const int cpx = nwg >> 3;
  const int swz = (bid & 7) * cpx + (bid >> 3);
  const int nbn = N >> 8;
  const int bn = swz % nbn, bm = swz / nbn;
  const int nkt = K >> 6;

  // per-lane staging source geometry
  const size_t rowK = (size_t)K * 2;
  const int off0 = wid * 1024 + lane * 16, off1 = off0 + 8192;
  const int r0 = off0 >> 7, r1 = off1 >> 7;
  const int c0 = ((off0 >> 4) & 7) ^ (r0 & 7);
  const int c1 = ((off1 >> 4) & 7) ^ (r1 & 7);
  const char* sA0 = (const char*)A + ((size_t)bm * 256 + r0) * rowK + c0 * 16;
  const char* sA1 = (const char*)A + ((size_t)bm * 256 + r1) * rowK + c1 * 16;
  const char* sB0 = (const char*)B + ((size_t)bn * 256 + r0) * rowK + c0 * 16;
  const char* sB1 = (const char*)B + ((size_t)bn * 256 + r1) * rowK + c1 * 16;
  const size_t hstep = (size_t)128 * rowK;

  int ht = 0;
  const int htmax = nkt * 4;
  auto stage = [&]() {
    if (ht < htmax) {
      const int kt_s = ht >> 2, part = ht & 3, db = kt_s & 1, hf = part & 1;
      const size_t goff = (size_t)kt_s * 128 + (hf ? hstep : (size_t)0);
      char* ldst;
      const char *g0, *g1;
      if (part < 2) { ldst = lds + 65536 + (db * 2 + hf) * 16384; g0 = sB0 + goff; g1 = sB1 + goff; }
      else          { ldst = lds + (db * 2 + hf) * 16384;          g0 = sA0 + goff; g1 = sA1 + goff; }
      gload_lds16(g0, ldst + wid * 1024);
      gload_lds16(g1, ldst + 8192 + wid * 1024);
      ht++;
    }
  };

  f32x4 acc[8][4] = {};
  const int xr = l15 & 7;
  const int ck0 = (lhi ^ xr) * 8;          // kk=0 chunk (elements)
  const int ck1 = (((4 + lhi) ^ xr)) * 8;  // kk=1 chunk

  // prologue: 7 half-tiles (K-tile 0 complete + 3 of K-tile 1)
  for (int i = 0; i < 7; ++i) stage();
  asm volatile("s_waitcnt vmcnt(6)" ::: "memory");
  BARRIER();

  for (int kt = 0; kt < nkt; ++kt) {
    const int d = kt & 1;
    const bf16_t* Asl = (const bf16_t*)(lds + (d * 2 + wr) * 16384);
    const bf16_t* Bsl = (const bf16_t*)(lds + 65536 + (d * 2 + (wc >> 1)) * 16384);
    bf16x8 a[4][2], b[4][2];
    // ---- phase 0: read A(mh=0) + all B; stage; MFMA quadrant (0,0) ----
#pragma unroll
    for (int mi = 0; mi < 4; ++mi) {
      const int ro = (mi * 16 + l15) * 64;
      a[mi][0] = *(const bf16x8*)(Asl + ro + ck0);
      a[mi][1] = *(const bf16x8*)(Asl + ro + ck1);
    }
#pragma unroll
    for (int n = 0; n < 4; ++n) {
      const int ro = ((wc & 1) * 64 + n * 16 + l15) * 64;
      b[n][0] = *(const bf16x8*)(Bsl + ro + ck0);
      b[n][1] = *(const bf16x8*)(Bsl + ro + ck1);
    }
    stage();
    BARRIER();
    __builtin_amdgcn_s_setprio(1);
#pragma unroll
    for (int mi = 0; mi < 4; ++mi)
#pragma unroll
      for (int ni = 0; ni < 2; ++ni) {
        acc[mi][ni] = MFMA16(a[mi][0], b[ni][0], acc[mi][ni]);
        acc[mi][ni] = MFMA16(a[mi][1], b[ni][1], acc[mi][ni]);
      }
    __builtin_amdgcn_s_setprio(0);
    BARRIER();
    // ---- phase 1: stage; MFMA quadrant (0,1) ----
    stage();
    BARRIER();
    __builtin_amdgcn_s_setprio(1);
#pragma unroll
    for (int mi = 0; mi < 4; ++mi)
#pragma unroll
      for (int ni = 0; ni < 2; ++ni) {
        acc[mi][2 + ni] = MFMA16(a[mi][0], b[2 + ni][0], acc[mi][2 + ni]);
        acc[mi][2 + ni] = MFMA16(a[mi][1], b[2 + ni][1], acc[mi][2 + ni]);
      }
    __builtin_amdgcn_s_setprio(0);
    BARRIER();
    // ---- phase 2: read A(mh=1); stage; MFMA quadrant (1,0) ----
#pragma unroll
    for (int mi = 0; mi < 4; ++mi) {
      const int ro = (64 + mi * 16 + l15) * 64;
      a[mi][0] = *(const bf16x8*)(Asl + ro + ck0);
      a[mi][1] = *(const bf16x8*)(Asl + ro + ck1);
    }
    stage();
    BARRIER();
    __builtin_amdgcn_s_setprio(1);
#pragma unroll
    for (int mi = 0; mi < 4; ++mi)
#pragma unroll
      for (int ni = 0; ni < 2; ++ni) {
        acc[4 + mi][ni] = MFMA16(a[mi][0], b[ni][0], acc[4 + mi][ni]);
        acc[4 + mi][ni] = MFMA16(a[mi][1], b[ni][1], acc[4 + mi][ni]);
      }
    __builtin_amdgcn_s_setprio(0);
    BARRIER();
    // ---- phase 3: stage; MFMA quadrant (1,1); counted vmcnt; barrier ----
    stage();
    BARRIER();
    __builtin_amdgcn_s_setprio(1);
#pragma unroll
    for (int mi = 0; mi < 4; ++mi)
#pragma unroll
      for (int ni = 0; ni < 2; ++ni) {
        acc[4 + mi][2 + ni] = MFMA16(a[mi][0], b[2 + ni][0], acc[4 + mi][2 + ni]);
        acc[4 + mi][2 + ni] = MFMA16(a[mi][1], b[2 + ni][1], acc[4 + mi][2 + ni]);
      }
    __builtin_amdgcn_s_setprio(0);
    if (kt >= nkt - 2) asm volatile("s_waitcnt vmcnt(0)" ::: "memory");
    else               asm volatile("s_waitcnt vmcnt(6)" ::: "memory");
    BARRIER();
  }

  // epilogue
#pragma unroll
  for (int m = 0; m < 8; ++m) {
    const int row0 = bm * 256 + wr * 128 + m * 16 + 4 * lhi;
#pragma unroll
    for (int n = 0; n < 4; ++n) {
      const int col = bn * 256 + wc * 64 + n * 16 + l15;
#pragma unroll
      for (int i = 0; i < 4; ++i)
        C[(size_t)(row0 + i) * N + col] = acc[m][n][i];
    }
  }
}

// ---------------- RMSNorm + RoPE + bf16 pack of Q/K/V ----------------
__global__ __launch_bounds__(256) void k_norm_rope(
    const float* __restrict__ qkv, const int* __restrict__ pos,
    const float* __restrict__ qw, const float* __restrict__ kw,
    bf16_t* __restrict__ Q, bf16_t* __restrict__ Kk, bf16_t* __restrict__ V) {
  const int w = blockIdx.x * 4 + (threadIdx.x >> 6);
  const int lane = threadIdx.x & 63;
  const int n = w / 48, slot = w % 48;
  const float* row = qkv + (size_t)n * 6144;
  if (slot >= 40) {
    const int h2 = slot - 40;
    float x0 = row[5120 + h2 * 128 + lane];
    float x1 = row[5120 + h2 * 128 + lane + 64];
    bf16_t* dst = V + ((size_t)n * 8 + h2) * 128;
    dst[lane] = (bf16_t)x0;
    dst[lane + 64] = (bf16_t)x1;
    return;
  }
  const bool isq = slot < 32;
  const int h = isq ? slot : slot - 32;
  const int coff = isq ? h * 128 : 4096 + h * 128;
  float x0 = row[coff + lane], x1 = row[coff + lane + 64];
  float ss = x0 * x0 + x1 * x1;
#pragma unroll
  for (int m = 32; m; m >>= 1) ss += __shfl_xor(ss, m, 64);
  const float inv = rsqrtf(ss * (1.0f / 128.0f) + 1e-6f);
  const float* wgt = isq ? qw : kw;
  float y0 = x0 * inv * wgt[lane];
  float y1 = x1 * inv * wgt[lane + 64];
  const float ang = (float)pos[n] * expf((float)lane * -0.14391156608f);
  float sn, cs;
  sincosf(ang, &sn, &cs);
  float o0 = y0 * cs - y1 * sn;
  float o1 = y1 * cs + y0 * sn;
  bf16_t* dst = isq ? (Q + ((size_t)n * 32 + h) * 128) : (Kk + ((size_t)n * 8 + h) * 128);
  dst[lane] = (bf16_t)o0;
  dst[lane + 64] = (bf16_t)o1;
}

// ---------------- causal GQA flash attention ----------------
__global__ __launch_bounds__(256, 2) void k_attn(
    const bf16_t* __restrict__ Q, const bf16_t* __restrict__ Kk,
    const bf16_t* __restrict__ V, bf16_t* __restrict__ O) {
  __shared__ __align__(16) bf16_t Ks[64 * 128];
  __shared__ __align__(16) bf16_t Vt[128 * 72];
  __shared__ __align__(16) bf16_t Ps[4][32 * 72];
  const int b = blockIdx.x;
  const int qb = b & 7, h = (b >> 3) & 31, s = b >> 8;
  const int kvh = h >> 2;
  const int tid = threadIdx.x, lane = tid & 63, wid = tid >> 6;
  const int l15 = lane & 15, lhi = lane >> 4;

  bf16x8 qf[2][4];
  {
    const int qrow = qb * 128 + wid * 32;
#pragma unroll
    for (int mt = 0; mt < 2; mt++) {
      const size_t base = ((size_t)(s * 1024 + qrow + mt * 16 + l15) * 32 + h) * 128;
#pragma unroll
      for (int kc = 0; kc < 4; kc++)
        qf[mt][kc] = *(const bf16x8*)(Q + base + kc * 32 + 8 * lhi);
    }
  }
  f32x4 of[2][8] = {};
  float mx[2][4], li[2][4];
#pragma unroll
  for (int mt = 0; mt < 2; mt++)
#pragma unroll
    for (int i = 0; i < 4; i++) { mx[mt][i] = -1e30f; li[mt][i] = 0.f; }

  const int ktiles = (qb + 1) * 2;
  const int vr_base = tid >> 4;
  const int vd0 = (tid & 15) * 8;

  for (int kt = 0; kt < ktiles; kt++) {
    const int kv0 = kt * 64;
#pragma unroll
    for (int c = 0; c < 4; c++) {
      const int wb = wid * 4096 + c * 1024;
      const int o = wb + lane * 16;
      const int krow = o >> 8;
      const int ci = (o >> 4) & 15;
      const int cs = ci ^ (krow & 7);
      const char* src =
          (const char*)(Kk + ((size_t)(s * 1024 + kv0 + krow) * 8 + kvh) * 128) + cs * 16;
      gload_lds16(src, (char*)Ks + wb);
    }
#pragma unroll
    for (int c = 0; c < 4; c++) {
      const int r = c * 16 + vr_base;
      bf16x8 v = *(const bf16x8*)(V + ((size_t)(s * 1024 + kv0 + r) * 8 + kvh) * 128 + vd0);
#pragma unroll
      for (int j = 0; j < 8; j++) {
        const int d = vd0 + j;
        const int cc = (r >> 3) ^ ((d >> 3) & 7);
        Vt[d * 72 + cc * 8 + (r & 7)] = v[j];
      }
    }
    __syncthreads();

    f32x4 sf[2][4] = {};
#pragma unroll
    for (int kc = 0; kc < 4; kc++) {
      bf16x8 kf[4];
#pragma unroll
      for (int n = 0; n < 4; n++) {
        const int krow = n * 16 + l15;
        const int ci = (kc * 4 + lhi) ^ (krow & 7);
        kf[n] = *(const bf16x8*)(Ks + krow * 128 + ci * 8);
      }
#pragma unroll
      for (int mt = 0; mt < 2; mt++)
#pragma unroll
        for (int n = 0; n < 4; n++)
          sf[mt][n] = MFMA16(qf[mt][kc], kf[n], sf[mt][n]);
    }

    const bool masked = (kt >= 2 * qb);
    const float scale = 0.08838834764831845f;
    float pv[2][4][4];
#pragma unroll
    for (int mt = 0; mt < 2; mt++) {
#pragma unroll
      for (int i = 0; i < 4; i++) {
        float rm = -1e30f;
#pragma unroll
        for (int n = 0; n < 4; n++) {
          float sv = sf[mt][n][i] * scale;
          if (masked) {
            const int kvg = kv0 + n * 16 + l15;
            const int qg = qb * 128 + wid * 32 + mt * 16 + 4 * lhi + i;
            if (kvg > qg) sv = -1e30f;
          }
          pv[mt][n][i] = sv;
          rm = fmaxf(rm, sv);
        }
#pragma unroll
        for (int mm = 1; mm < 16; mm <<= 1) rm = fmaxf(rm, __shfl_xor(rm, mm, 64));
        const float nm = fmaxf(mx[mt][i], rm);
        float ts = 0.f;
#pragma unroll
        for (int n = 0; n < 4; n++) {
          float e = __expf(pv[mt][n][i] - nm);
          pv[mt][n][i] = e;
          ts += e;
        }
#pragma unroll
        for (int mm = 1; mm < 16; mm <<= 1) ts += __shfl_xor(ts, mm, 64);
        const float al = __expf(mx[mt][i] - nm);
        li[mt][i] = li[mt][i] * al + ts;
        mx[mt][i] = nm;
#pragma unroll
        for (int n = 0; n < 8; n++) of[mt][n][i] *= al;
      }
    }

    bf16_t* myP = &Ps[wid][0];
#pragma unroll
    for (int mt = 0; mt < 2; mt++)
#pragma unroll
      for (int n = 0; n < 4; n++)
#pragma unroll
        for (int i = 0; i < 4; i++)
          myP[(mt * 16 + 4 * lhi + i) * 72 + n * 16 + l15] = (bf16_t)pv[mt][n][i];

#pragma unroll
    for (int kc = 0; kc < 2; kc++) {
      bf16x8 pf[2];
#pragma unroll
      for (int mt = 0; mt < 2; mt++)
        pf[mt] = *(const bf16x8*)(myP + (mt * 16 + l15) * 72 + kc * 32 + 8 * lhi);
#pragma unroll
      for (int n = 0; n < 8; n++) {
        const int d = n * 16 + l15;
        const int cc = (kc * 4 + lhi) ^ ((d >> 3) & 7);
        bf16x8 vf = *(const bf16x8*)(Vt + d * 72 + cc * 8);
#pragma unroll
        for (int mt = 0; mt < 2; mt++)
          of[mt][n] = MFMA16(pf[mt], vf, of[mt][n]);
      }
    }
    __syncthreads();
  }

#pragma unroll
  for (int mt = 0; mt < 2; mt++) {
#pragma unroll
    for (int i = 0; i < 4; i++) {
      const float invl = 1.0f / li[mt][i];
      const int tokrow = qb * 128 + wid * 32 + mt * 16 + 4 * lhi + i;
      bf16_t* dst = O + (size_t)(s * 1024 + tokrow) * 4096 + h * 128;
#pragma unroll
      for (int n = 0; n < 8; n++)
        dst[n * 16 + l15] = (bf16_t)(of[mt][n][i] * invl);
    }
  }
}

// ---------------- launch ----------------
extern "C" void kernel_launch(void* const* d_in, const int* in_sizes, int n_in,
                              void* d_out, int out_size, void* d_ws, size_t ws_size,
                              hipStream_t stream) {
  const float* hidden = (const float*)d_in[0];
  const float* mu     = (const float*)d_in[1];
  const int*   pos    = (const int*)d_in[2];
  const float* Wq  = (const float*)d_in[3];
  const float* Wk  = (const float*)d_in[4];
  const float* Wv  = (const float*)d_in[5];
  const float* Wo  = (const float*)d_in[6];
  const float* Wmq = (const float*)d_in[7];
  const float* Wmk = (const float*)d_in[8];
  const float* Wmv = (const float*)d_in[9];
  const float* qw  = (const float*)d_in[10];
  const float* kw  = (const float*)d_in[11];
  float* out = (float*)d_out;
  char* ws = (char*)d_ws;

  if (ws_size < 301989888u) return;  // need 288 MiB

  bf16_t* Wqkv = (bf16_t*)(ws);                    // [6144][8192] bf16
  bf16_t* Wob  = (bf16_t*)(ws + 100663296);        // [4096][4096] bf16
  bf16_t* Xb   = (bf16_t*)(ws + 134217728);        // [4096][8192] bf16
  bf16_t* Qb   = (bf16_t*)(ws + 134217728);        // aliases Xb (dead after GEMM1)
  bf16_t* Kb   = (bf16_t*)(ws + 167772160);
  bf16_t* Vb   = (bf16_t*)(ws + 176160768);
  float*  qkv  = (float*)(ws + 201326592);         // [4096][6144] f32
  bf16_t* Ob   = (bf16_t*)(ws + 201326592);        // aliases qkv (dead after norm/rope)

  k_pack_pair<<<2048, 256, 0, stream>>>(hidden, mu, Xb, 4096);
  k_pack_pair<<<2048, 256, 0, stream>>>(Wq, Wmq, Wqkv, 4096);
  k_pack_pair<<<1024, 256, 0, stream>>>(Wk, Wmk, Wqkv + (size_t)4096 * 8192, 1024);
  k_pack_pair<<<1024, 256, 0, stream>>>(Wv, Wmv, Wqkv + (size_t)5120 * 8192, 1024);
  k_convert<<<2048, 256, 0, stream>>>(Wo, Wob, (size_t)4096 * 4096 / 4);

  k_gemm256<<<384, 512, 0, stream>>>(Xb, Wqkv, qkv, 4096, 6144, 8192);
  k_norm_rope<<<49152, 256, 0, stream>>>(qkv, pos, qw, kw, Qb, Kb, Vb);
  k_attn<<<1024, 256, 0, stream>>>(Qb, Kb, Vb, Ob);
  k_gemm256<<<256, 512, 0, stream>>>(Ob, Wob, out, 4096, 4096, 4096);
}

// Round 3
// 849.594 us; speedup vs baseline: 1.1403x; 1.1403x over previous
//
#include <hip/hip_runtime.h>
#include <hip/hip_bf16.h>
#include <stdint.h>

#define DEV static __device__ __forceinline__

typedef __bf16 bf16_t;
typedef __bf16 bf16x8 __attribute__((ext_vector_type(8)));
typedef __bf16 bf16x4 __attribute__((ext_vector_type(4)));
typedef float  f32x4  __attribute__((ext_vector_type(4)));

// H=32 q heads, KV=8 kv heads, D=128, HID=4096, S=4, L=1024, N=4096

DEV void gload_lds16(const void* g, void* l) {
  __builtin_amdgcn_global_load_lds(
      (__attribute__((address_space(1))) void*)(uintptr_t)(g),
      (__attribute__((address_space(3))) void*)(uintptr_t)(l),
      16, 0, 0);
}

#define BARRIER() asm volatile("s_barrier" ::: "memory")
#define MFMA16(a, b, c) __builtin_amdgcn_mfma_f32_16x16x32_bf16((a), (b), (c), 0, 0, 0)

// ---------------- pack/convert kernels ----------------
__global__ void k_pack_pair(const float* __restrict__ A, const float* __restrict__ B,
                            bf16_t* __restrict__ dst, int rows) {
  size_t n4 = (size_t)rows * 1024;
  size_t stride = (size_t)gridDim.x * blockDim.x;
  for (size_t i = (size_t)blockIdx.x * blockDim.x + threadIdx.x; i < n4; i += stride) {
    size_t r = i >> 10, c4 = i & 1023;
    float4 va = ((const float4*)A)[i];
    float4 vb = ((const float4*)B)[i];
    bf16x4 oa = { (bf16_t)va.x, (bf16_t)va.y, (bf16_t)va.z, (bf16_t)va.w };
    bf16x4 ob = { (bf16_t)vb.x, (bf16_t)vb.y, (bf16_t)vb.z, (bf16_t)vb.w };
    ((bf16x4*)dst)[r * 2048 + c4]        = oa;
    ((bf16x4*)dst)[r * 2048 + 1024 + c4] = ob;
  }
}

__global__ void k_convert(const float* __restrict__ A, bf16_t* __restrict__ dst, size_t n4) {
  size_t stride = (size_t)gridDim.x * blockDim.x;
  for (size_t i = (size_t)blockIdx.x * blockDim.x + threadIdx.x; i < n4; i += stride) {
    float4 v = ((const float4*)A)[i];
    bf16x4 o = { (bf16_t)v.x, (bf16_t)v.y, (bf16_t)v.z, (bf16_t)v.w };
    ((bf16x4*)dst)[i] = o;
  }
}

// ---------------- 256x256 8-phase bf16 GEMM: C = A[M][K] * B[N][K]^T ----------------
// 512 threads = 8 waves (2M x 4N), BK=64. LDS ring 128 KiB, 16B-chunk XOR swizzle.
// NSPLIT: K split into NSPLIT slices; slice ks writes partial C at C + ks*M*N (dtype CT).
// ds_read distribution per K-tile: 12 (A-mh0 + B-nh0), 4 (B-nh1), 8 (A-mh1), 0.
// vmcnt(6) once per K-tile; drain to 0 only on last two tiles.
template<typename CT, int NSPLIT>
__global__ __launch_bounds__(512, 2) void k_gemm256(
    const bf16_t* __restrict__ A, const bf16_t* __restrict__ B,
    CT* __restrict__ C, int M, int N, int Kfull) {
  __shared__ __align__(16) char lds[131072];
  const int tid = threadIdx.x, lane = tid & 63, wid = tid >> 6;
  const int l15 = lane & 15, lhi = lane >> 4;
  const int wr = wid >> 2, wc = wid & 3;
  // bijective XCD swizzle (nwg % 8 == 0 for all our launches)
  const int bid = blockIdx.x, nwg = gridDim.x;
  const int cpx = nwg >> 3;
  const int swz = (bid & 7) * cpx + (bid >> 3);
  const int nbn = N >> 8;
  const int tiles = (M >> 8) * nbn;
  const int ks = (NSPLIT > 1) ? (swz / tiles) : 0;
  const int t  = (NSPLIT > 1) ? (swz % tiles) : swz;
  const int bn = t % nbn, bm = t / nbn;
  const int Kloop = Kfull / NSPLIT;
  const int nkt = Kloop >> 6;

  // per-lane staging source geometry (inverse-swizzled global source, linear LDS dest)
  const size_t rowK = (size_t)Kfull * 2;
  const size_t kbase = (size_t)ks * Kloop * 2;
  const int off0 = wid * 1024 + lane * 16, off1 = off0 + 8192;
  const int r0 = off0 >> 7, r1 = off1 >> 7;
  const int c0 = ((off0 >> 4) & 7) ^ (r0 & 7);
  const int c1 = ((off1 >> 4) & 7) ^ (r1 & 7);
  const char* sA0 = (const char*)A + ((size_t)bm * 256 + r0) * rowK + kbase + c0 * 16;
  const char* sA1 = (const char*)A + ((size_t)bm * 256 + r1) * rowK + kbase + c1 * 16;
  const char* sB0 = (const char*)B + ((size_t)bn * 256 + r0) * rowK + kbase + c0 * 16;
  const char* sB1 = (const char*)B + ((size_t)bn * 256 + r1) * rowK + kbase + c1 * 16;
  const size_t hstep = (size_t)128 * rowK;

  int ht = 0;
  const int htmax = nkt * 4;
  auto stage = [&]() {
    if (ht < htmax) {
      const int kt_s = ht >> 2, part = ht & 3, db = kt_s & 1, hf = part & 1;
      const size_t goff = (size_t)kt_s * 128 + (hf ? hstep : (size_t)0);
      char* ldst;
      const char *g0, *g1;
      if (part < 2) { ldst = lds + 65536 + (db * 2 + hf) * 16384; g0 = sB0 + goff; g1 = sB1 + goff; }
      else          { ldst = lds + (db * 2 + hf) * 16384;          g0 = sA0 + goff; g1 = sA1 + goff; }
      gload_lds16(g0, ldst + wid * 1024);
      gload_lds16(g1, ldst + 8192 + wid * 1024);
      ht++;
    }
  };

  f32x4 acc[8][4] = {};
  const int xr = l15 & 7;
  const int ck0 = (lhi ^ xr) * 8;
  const int ck1 = (((4 + lhi) ^ xr)) * 8;

  // prologue: 7 half-tiles (K-tile 0 complete + 3 of K-tile 1)
  for (int i = 0; i < 7; ++i) stage();
  asm volatile("s_waitcnt vmcnt(6)" ::: "memory");
  BARRIER();

  for (int kt = 0; kt < nkt; ++kt) {
    const int d = kt & 1;
    const bf16_t* Asl = (const bf16_t*)(lds + (d * 2 + wr) * 16384);
    const bf16_t* Bsl = (const bf16_t*)(lds + 65536 + (d * 2 + (wc >> 1)) * 16384);
    bf16x8 a[4][2], b[4][2];
    // ---- phase 0: read A(mh0) 8 + B(nh0) 4; stage; MFMA q(0, n0-1) ----
#pragma unroll
    for (int mi = 0; mi < 4; ++mi) {
      const int ro = (mi * 16 + l15) * 64;
      a[mi][0] = *(const bf16x8*)(Asl + ro + ck0);
      a[mi][1] = *(const bf16x8*)(Asl + ro + ck1);
    }
#pragma unroll
    for (int n = 0; n < 2; ++n) {
      const int ro = ((wc & 1) * 64 + n * 16 + l15) * 64;
      b[n][0] = *(const bf16x8*)(Bsl + ro + ck0);
      b[n][1] = *(const bf16x8*)(Bsl + ro + ck1);
    }
    stage();
    asm volatile("s_waitcnt lgkmcnt(8)" ::: "memory");
    BARRIER();
    __builtin_amdgcn_s_setprio(1);
#pragma unroll
    for (int mi = 0; mi < 4; ++mi)
#pragma unroll
      for (int ni = 0; ni < 2; ++ni) {
        acc[mi][ni] = MFMA16(a[mi][0], b[ni][0], acc[mi][ni]);
        acc[mi][ni] = MFMA16(a[mi][1], b[ni][1], acc[mi][ni]);
      }
    __builtin_amdgcn_s_setprio(0);
    BARRIER();
    // ---- phase 1: read B(nh1) 4; stage; MFMA q(0, n2-3) ----
#pragma unroll
    for (int n = 2; n < 4; ++n) {
      const int ro = ((wc & 1) * 64 + n * 16 + l15) * 64;
      b[n][0] = *(const bf16x8*)(Bsl + ro + ck0);
      b[n][1] = *(const bf16x8*)(Bsl + ro + ck1);
    }
    stage();
    BARRIER();
    __builtin_amdgcn_s_setprio(1);
#pragma unroll
    for (int mi = 0; mi < 4; ++mi)
#pragma unroll
      for (int ni = 0; ni < 2; ++ni) {
        acc[mi][2 + ni] = MFMA16(a[mi][0], b[2 + ni][0], acc[mi][2 + ni]);
        acc[mi][2 + ni] = MFMA16(a[mi][1], b[2 + ni][1], acc[mi][2 + ni]);
      }
    __builtin_amdgcn_s_setprio(0);
    BARRIER();
    // ---- phase 2: read A(mh1) 8; stage; MFMA q(1, n0-1) ----
#pragma unroll
    for (int mi = 0; mi < 4; ++mi) {
      const int ro = (64 + mi * 16 + l15) * 64;
      a[mi][0] = *(const bf16x8*)(Asl + ro + ck0);
      a[mi][1] = *(const bf16x8*)(Asl + ro + ck1);
    }
    stage();
    BARRIER();
    __builtin_amdgcn_s_setprio(1);
#pragma unroll
    for (int mi = 0; mi < 4; ++mi)
#pragma unroll
      for (int ni = 0; ni < 2; ++ni) {
        acc[4 + mi][ni] = MFMA16(a[mi][0], b[ni][0], acc[4 + mi][ni]);
        acc[4 + mi][ni] = MFMA16(a[mi][1], b[ni][1], acc[4 + mi][ni]);
      }
    __builtin_amdgcn_s_setprio(0);
    BARRIER();
    // ---- phase 3: stage; MFMA q(1, n2-3); counted vmcnt; barrier ----
    stage();
    BARRIER();
    __builtin_amdgcn_s_setprio(1);
#pragma unroll
    for (int mi = 0; mi < 4; ++mi)
#pragma unroll
      for (int ni = 0; ni < 2; ++ni) {
        acc[4 + mi][2 + ni] = MFMA16(a[mi][0], b[2 + ni][0], acc[4 + mi][2 + ni]);
        acc[4 + mi][2 + ni] = MFMA16(a[mi][1], b[2 + ni][1], acc[4 + mi][2 + ni]);
      }
    __builtin_amdgcn_s_setprio(0);
    if (kt >= nkt - 2) asm volatile("s_waitcnt vmcnt(0)" ::: "memory");
    else               asm volatile("s_waitcnt vmcnt(6)" ::: "memory");
    BARRIER();
  }

  // epilogue: write (partial) C
  CT* Cp = C + (size_t)ks * M * N;
#pragma unroll
  for (int m = 0; m < 8; ++m) {
    const int row0 = bm * 256 + wr * 128 + m * 16 + 4 * lhi;
#pragma unroll
    for (int n = 0; n < 4; ++n) {
      const int col = bn * 256 + wc * 64 + n * 16 + l15;
#pragma unroll
      for (int i = 0; i < 4; ++i)
        Cp[(size_t)(row0 + i) * N + col] = (CT)acc[m][n][i];
    }
  }
}

// ---------------- RMSNorm + RoPE + bf16 pack of Q/K/V (sums split-K partials) ----------------
__global__ __launch_bounds__(256) void k_norm_rope(
    const bf16_t* __restrict__ qkvA, const bf16_t* __restrict__ qkvB,
    const int* __restrict__ pos,
    const float* __restrict__ qw, const float* __restrict__ kw,
    bf16_t* __restrict__ Q, bf16_t* __restrict__ Kk, bf16_t* __restrict__ V) {
  const int w = blockIdx.x * 4 + (threadIdx.x >> 6);
  const int lane = threadIdx.x & 63;
  const int n = w / 48, slot = w % 48;
  const bf16_t* rowA = qkvA + (size_t)n * 6144;
  const bf16_t* rowB = qkvB + (size_t)n * 6144;
  if (slot >= 40) {
    const int h2 = slot - 40;
    const int c = 5120 + h2 * 128 + lane;
    float x0 = (float)rowA[c] + (float)rowB[c];
    float x1 = (float)rowA[c + 64] + (float)rowB[c + 64];
    bf16_t* dst = V + ((size_t)n * 8 + h2) * 128;
    dst[lane] = (bf16_t)x0;
    dst[lane + 64] = (bf16_t)x1;
    return;
  }
  const bool isq = slot < 32;
  const int h = isq ? slot : slot - 32;
  const int coff = (isq ? h * 128 : 4096 + h * 128) + lane;
  float x0 = (float)rowA[coff] + (float)rowB[coff];
  float x1 = (float)rowA[coff + 64] + (float)rowB[coff + 64];
  float ss = x0 * x0 + x1 * x1;
#pragma unroll
  for (int m = 32; m; m >>= 1) ss += __shfl_xor(ss, m, 64);
  const float inv = rsqrtf(ss * (1.0f / 128.0f) + 1e-6f);
  const float* wgt = isq ? qw : kw;
  float y0 = x0 * inv * wgt[lane];
  float y1 = x1 * inv * wgt[lane + 64];
  const float ang = (float)pos[n] * expf((float)lane * -0.14391156608f);
  float sn, cs;
  sincosf(ang, &sn, &cs);
  float o0 = y0 * cs - y1 * sn;
  float o1 = y1 * cs + y0 * sn;
  bf16_t* dst = isq ? (Q + ((size_t)n * 32 + h) * 128) : (Kk + ((size_t)n * 8 + h) * 128);
  dst[lane] = (bf16_t)o0;
  dst[lane + 64] = (bf16_t)o1;
}

// ---------------- causal GQA flash attention ----------------
__global__ __launch_bounds__(256, 2) void k_attn(
    const bf16_t* __restrict__ Q, const bf16_t* __restrict__ Kk,
    const bf16_t* __restrict__ V, bf16_t* __restrict__ O) {
  __shared__ __align__(16) bf16_t Ks[64 * 128];
  __shared__ __align__(16) bf16_t Vt[128 * 72];
  __shared__ __align__(16) bf16_t Ps[4][32 * 72];
  const int b = blockIdx.x;
  const int qb = b & 7, h = (b >> 3) & 31, s = b >> 8;
  const int kvh = h >> 2;
  const int tid = threadIdx.x, lane = tid & 63, wid = tid >> 6;
  const int l15 = lane & 15, lhi = lane >> 4;

  bf16x8 qf[2][4];
  {
    const int qrow = qb * 128 + wid * 32;
#pragma unroll
    for (int mt = 0; mt < 2; mt++) {
      const size_t base = ((size_t)(s * 1024 + qrow + mt * 16 + l15) * 32 + h) * 128;
#pragma unroll
      for (int kc = 0; kc < 4; kc++)
        qf[mt][kc] = *(const bf16x8*)(Q + base + kc * 32 + 8 * lhi);
    }
  }
  f32x4 of[2][8] = {};
  float mx[2][4], li[2][4];
#pragma unroll
  for (int mt = 0; mt < 2; mt++)
#pragma unroll
    for (int i = 0; i < 4; i++) { mx[mt][i] = -1e30f; li[mt][i] = 0.f; }

  const int ktiles = (qb + 1) * 2;
  const int vr_base = tid >> 4;
  const int vd0 = (tid & 15) * 8;

  for (int kt = 0; kt < ktiles; kt++) {
    const int kv0 = kt * 64;
#pragma unroll
    for (int c = 0; c < 4; c++) {
      const int wb = wid * 4096 + c * 1024;
      const int o = wb + lane * 16;
      const int krow = o >> 8;
      const int ci = (o >> 4) & 15;
      const int cs = ci ^ (krow & 7);
      const char* src =
          (const char*)(Kk + ((size_t)(s * 1024 + kv0 + krow) * 8 + kvh) * 128) + cs * 16;
      gload_lds16(src, (char*)Ks + wb);
    }
#pragma unroll
    for (int c = 0; c < 4; c++) {
      const int r = c * 16 + vr_base;
      bf16x8 v = *(const bf16x8*)(V + ((size_t)(s * 1024 + kv0 + r) * 8 + kvh) * 128 + vd0);
#pragma unroll
      for (int j = 0; j < 8; j++) {
        const int d = vd0 + j;
        const int cc = (r >> 3) ^ ((d >> 3) & 7);
        Vt[d * 72 + cc * 8 + (r & 7)] = v[j];
      }
    }
    __syncthreads();

    f32x4 sf[2][4] = {};
#pragma unroll
    for (int kc = 0; kc < 4; kc++) {
      bf16x8 kf[4];
#pragma unroll
      for (int n = 0; n < 4; n++) {
        const int krow = n * 16 + l15;
        const int ci = (kc * 4 + lhi) ^ (krow & 7);
        kf[n] = *(const bf16x8*)(Ks + krow * 128 + ci * 8);
      }
#pragma unroll
      for (int mt = 0; mt < 2; mt++)
#pragma unroll
        for (int n = 0; n < 4; n++)
          sf[mt][n] = MFMA16(qf[mt][kc], kf[n], sf[mt][n]);
    }

    const bool masked = (kt >= 2 * qb);
    const float scale = 0.08838834764831845f;
    float pv[2][4][4];
#pragma unroll
    for (int mt = 0; mt < 2; mt++) {
#pragma unroll
      for (int i = 0; i < 4; i++) {
        float rm = -1e30f;
#pragma unroll
        for (int n = 0; n < 4; n++) {
          float sv = sf[mt][n][i] * scale;
          if (masked) {
            const int kvg = kv0 + n * 16 + l15;
            const int qg = qb * 128 + wid * 32 + mt * 16 + 4 * lhi + i;
            if (kvg > qg) sv = -1e30f;
          }
          pv[mt][n][i] = sv;
          rm = fmaxf(rm, sv);
        }
#pragma unroll
        for (int mm = 1; mm < 16; mm <<= 1) rm = fmaxf(rm, __shfl_xor(rm, mm, 64));
        const float nm = fmaxf(mx[mt][i], rm);
        float ts = 0.f;
#pragma unroll
        for (int n = 0; n < 4; n++) {
          float e = __expf(pv[mt][n][i] - nm);
          pv[mt][n][i] = e;
          ts += e;
        }
#pragma unroll
        for (int mm = 1; mm < 16; mm <<= 1) ts += __shfl_xor(ts, mm, 64);
        const float al = __expf(mx[mt][i] - nm);
        li[mt][i] = li[mt][i] * al + ts;
        mx[mt][i] = nm;
#pragma unroll
        for (int n = 0; n < 8; n++) of[mt][n][i] *= al;
      }
    }

    bf16_t* myP = &Ps[wid][0];
#pragma unroll
    for (int mt = 0; mt < 2; mt++)
#pragma unroll
      for (int n = 0; n < 4; n++)
#pragma unroll
        for (int i = 0; i < 4; i++)
          myP[(mt * 16 + 4 * lhi + i) * 72 + n * 16 + l15] = (bf16_t)pv[mt][n][i];

#pragma unroll
    for (int kc = 0; kc < 2; kc++) {
      bf16x8 pf[2];
#pragma unroll
      for (int mt = 0; mt < 2; mt++)
        pf[mt] = *(const bf16x8*)(myP + (mt * 16 + l15) * 72 + kc * 32 + 8 * lhi);
#pragma unroll
      for (int n = 0; n < 8; n++) {
        const int d = n * 16 + l15;
        const int cc = (kc * 4 + lhi) ^ ((d >> 3) & 7);
        bf16x8 vf = *(const bf16x8*)(Vt + d * 72 + cc * 8);
#pragma unroll
        for (int mt = 0; mt < 2; mt++)
          of[mt][n] = MFMA16(pf[mt], vf, of[mt][n]);
      }
    }
    __syncthreads();
  }

#pragma unroll
  for (int mt = 0; mt < 2; mt++) {
#pragma unroll
    for (int i = 0; i < 4; i++) {
      const float invl = 1.0f / li[mt][i];
      const int tokrow = qb * 128 + wid * 32 + mt * 16 + 4 * lhi + i;
      bf16_t* dst = O + (size_t)(s * 1024 + tokrow) * 4096 + h * 128;
#pragma unroll
      for (int n = 0; n < 8; n++)
        dst[n * 16 + l15] = (bf16_t)(of[mt][n][i] * invl);
    }
  }
}

// ---------------- launch ----------------
extern "C" void kernel_launch(void* const* d_in, const int* in_sizes, int n_in,
                              void* d_out, int out_size, void* d_ws, size_t ws_size,
                              hipStream_t stream) {
  const float* hidden = (const float*)d_in[0];
  const float* mu     = (const float*)d_in[1];
  const int*   pos    = (const int*)d_in[2];
  const float* Wq  = (const float*)d_in[3];
  const float* Wk  = (const float*)d_in[4];
  const float* Wv  = (const float*)d_in[5];
  const float* Wo  = (const float*)d_in[6];
  const float* Wmq = (const float*)d_in[7];
  const float* Wmk = (const float*)d_in[8];
  const float* Wmv = (const float*)d_in[9];
  const float* qw  = (const float*)d_in[10];
  const float* kw  = (const float*)d_in[11];
  float* out = (float*)d_out;
  char* ws = (char*)d_ws;

  if (ws_size < 301989888u) return;  // need 288 MiB

  bf16_t* Wqkv = (bf16_t*)(ws);                    // [6144][8192] bf16   0..96MiB
  bf16_t* Wob  = (bf16_t*)(ws + 100663296);        // [4096][4096] bf16   96..128MiB
  bf16_t* Xb   = (bf16_t*)(ws + 134217728);        // [4096][8192] bf16   128..192MiB
  bf16_t* Qb   = (bf16_t*)(ws + 134217728);        // aliases Xb (dead after GEMM1) 32MiB
  bf16_t* Kb   = (bf16_t*)(ws + 167772160);        // 8MiB
  bf16_t* Vb   = (bf16_t*)(ws + 176160768);        // 8MiB
  bf16_t* qkvA = (bf16_t*)(ws + 201326592);        // [4096][6144] bf16 partial ks=0 (48MiB)
  bf16_t* qkvB = (bf16_t*)(ws + 251658240);        // partial ks=1 (48MiB), contiguous after A
  bf16_t* Ob   = (bf16_t*)(ws + 201326592);        // aliases qkvA (dead after norm/rope) 32MiB

  k_pack_pair<<<2048, 256, 0, stream>>>(hidden, mu, Xb, 4096);
  k_pack_pair<<<2048, 256, 0, stream>>>(Wq, Wmq, Wqkv, 4096);
  k_pack_pair<<<1024, 256, 0, stream>>>(Wk, Wmk, Wqkv + (size_t)4096 * 8192, 1024);
  k_pack_pair<<<1024, 256, 0, stream>>>(Wv, Wmv, Wqkv + (size_t)5120 * 8192, 1024);
  k_convert<<<2048, 256, 0, stream>>>(Wo, Wob, (size_t)4096 * 4096 / 4);

  k_gemm256<bf16_t, 2><<<768, 512, 0, stream>>>(Xb, Wqkv, qkvA, 4096, 6144, 8192);
  k_norm_rope<<<49152, 256, 0, stream>>>(qkvA, qkvB, pos, qw, kw, Qb, Kb, Vb);
  k_attn<<<1024, 256, 0, stream>>>(Qb, Kb, Vb, Ob);
  k_gemm256<float, 1><<<256, 512, 0, stream>>>(Ob, Wob, out, 4096, 4096, 4096);
}

// Round 5
// 783.434 us; speedup vs baseline: 1.2366x; 1.0844x over previous
//
#include <hip/hip_runtime.h>
#include <hip/hip_bf16.h>
#include <stdint.h>

#define DEV static __device__ __forceinline__

typedef __bf16 bf16_t;
typedef __bf16 bf16x8 __attribute__((ext_vector_type(8)));
typedef __bf16 bf16x4 __attribute__((ext_vector_type(4)));
typedef float  f32x4  __attribute__((ext_vector_type(4)));

// H=32 q heads, KV=8 kv heads, D=128, HID=4096, S=4, L=1024, N=4096

DEV void gload_lds16(const void* g, void* l) {
  __builtin_amdgcn_global_load_lds(
      (__attribute__((address_space(1))) void*)(uintptr_t)(g),
      (__attribute__((address_space(3))) void*)(uintptr_t)(l),
      16, 0, 0);
}

#define BARRIER() asm volatile("s_barrier" ::: "memory")
#define MFMA16(a, b, c) __builtin_amdgcn_mfma_f32_16x16x32_bf16((a), (b), (c), 0, 0, 0)

// ---------------- unified pack/convert kernel ----------------
DEV void pack_pair_chunk(const float* __restrict__ A, const float* __restrict__ B,
                         bf16_t* __restrict__ dst, size_t i) {
  size_t r = i >> 10, c = i & 1023;
  float4 va = ((const float4*)A)[i];
  float4 vb = ((const float4*)B)[i];
  bf16x4 oa = {(bf16_t)va.x, (bf16_t)va.y, (bf16_t)va.z, (bf16_t)va.w};
  bf16x4 ob = {(bf16_t)vb.x, (bf16_t)vb.y, (bf16_t)vb.z, (bf16_t)vb.w};
  ((bf16x4*)dst)[r * 2048 + c] = oa;
  ((bf16x4*)dst)[r * 2048 + 1024 + c] = ob;
}

__global__ void k_pack_all(const float* __restrict__ hidden, const float* __restrict__ mu,
                           const float* __restrict__ Wq, const float* __restrict__ Wmq,
                           const float* __restrict__ Wk, const float* __restrict__ Wmk,
                           const float* __restrict__ Wv, const float* __restrict__ Wmv,
                           const float* __restrict__ Wo,
                           bf16_t* __restrict__ Xb, bf16_t* __restrict__ Wqkv,
                           bf16_t* __restrict__ Wob) {
  const size_t t0 = 4194304, t1 = 8388608, t2 = 9437184, t3 = 10485760, t4 = 14680064;
  size_t stride = (size_t)gridDim.x * blockDim.x;
  for (size_t i = (size_t)blockIdx.x * blockDim.x + threadIdx.x; i < t4; i += stride) {
    if (i < t0) {
      pack_pair_chunk(hidden, mu, Xb, i);
    } else if (i < t1) {
      pack_pair_chunk(Wq, Wmq, Wqkv, i - t0);
    } else if (i < t2) {
      pack_pair_chunk(Wk, Wmk, Wqkv + (size_t)4096 * 8192, i - t1);
    } else if (i < t3) {
      pack_pair_chunk(Wv, Wmv, Wqkv + (size_t)5120 * 8192, i - t2);
    } else {
      size_t j = i - t3;
      float4 v = ((const float4*)Wo)[j];
      bf16x4 o = {(bf16_t)v.x, (bf16_t)v.y, (bf16_t)v.z, (bf16_t)v.w};
      ((bf16x4*)Wob)[j] = o;
    }
  }
}

// ---------------- 256x256 8-phase bf16 GEMM: C = A[M][K] * B[N][K]^T ----------------
// 512 threads = 8 waves (2M x 4N), BK=64 (= 128 BYTES of K per tile). LDS ring 128 KiB,
// 16B-chunk XOR swizzle (inverse-swizzled global source -> linear LDS dest; swizzled ds_read).
// kt-unrolled x2: even tiles use slots A0/A1/B0/B1, odd tiles A2/A3/B2/B3.
// Read distribution 16/0/8/0 (race-free: every stage lands >=1 closing barrier after
// the last ds_read of its slot). vmcnt(6) once per K-tile; drain 0 only at the tail.
// bm-fast tile order so XCD-neighbor WGs share B panels in L2.
template<typename CT, int NSPLIT>
__global__ __launch_bounds__(512, 2) void k_gemm256(
    const bf16_t* __restrict__ A, const bf16_t* __restrict__ B,
    CT* __restrict__ C, int M, int N, int Kfull) {
  __shared__ __align__(16) char lds[131072];
  const int tid = threadIdx.x, lane = tid & 63, wid = tid >> 6;
  const int l15 = lane & 15, lhi = lane >> 4;
  const int wr = wid >> 2, wc = wid & 3;
  // bijective XCD swizzle (nwg % 8 == 0 for all our launches)
  const int bid = blockIdx.x, nwg = gridDim.x;
  const int cpx = nwg >> 3;
  const int swz = (bid & 7) * cpx + (bid >> 3);
  const int nbm = M >> 8;
  const int tiles = nbm * (N >> 8);
  const int ks = (NSPLIT > 1) ? (swz / tiles) : 0;
  const int t  = (NSPLIT > 1) ? (swz % tiles) : swz;
  const int bm = t % nbm, bn = t / nbm;   // bm-fast
  const int Kloop = Kfull / NSPLIT;
  const int nkt = Kloop >> 6;

  const size_t rowK = (size_t)Kfull * 2;
  const size_t kbase = (size_t)ks * Kloop * 2;
  const int off0 = wid * 1024 + lane * 16, off1 = off0 + 8192;
  const int r0 = off0 >> 7, r1 = off1 >> 7;
  const int c0 = ((off0 >> 4) & 7) ^ (r0 & 7);
  const int c1 = ((off1 >> 4) & 7) ^ (r1 & 7);
  const char* sA0 = (const char*)A + ((size_t)bm * 256 + r0) * rowK + kbase + c0 * 16;
  const char* sA1 = (const char*)A + ((size_t)bm * 256 + r1) * rowK + kbase + c1 * 16;
  const char* sB0 = (const char*)B + ((size_t)bn * 256 + r0) * rowK + kbase + c0 * 16;
  const char* sB1 = (const char*)B + ((size_t)bn * 256 + r1) * rowK + kbase + c1 * 16;
  const size_t hst = (size_t)128 * rowK;

  enum { A0S = 0, A1S = 16384, A2S = 32768, A3S = 49152,
         B0S = 65536, B1S = 81920, B2S = 98304, B3S = 114688 };

#define STG(slot, pa, pb, off) do { \
    gload_lds16((pa) + (off), lds + (slot) + wid * 1024); \
    gload_lds16((pb) + (off), lds + (slot) + 8192 + wid * 1024); } while (0)

  const bf16_t* Ae = (const bf16_t*)(lds + A0S + wr * 16384);
  const bf16_t* Be = (const bf16_t*)(lds + B0S + (wc >> 1) * 16384);
  const bf16_t* Ao = (const bf16_t*)(lds + A2S + wr * 16384);
  const bf16_t* Bo = (const bf16_t*)(lds + B2S + (wc >> 1) * 16384);
  const int bro = (wc & 1) * 64;

  f32x4 acc[8][4] = {};
  bf16x8 a[4][2], b[4][2];
  const int xr = l15 & 7;
  const int ck0 = (lhi ^ xr) * 8;
  const int ck1 = ((4 + lhi) ^ xr) * 8;

#define RD_A(base, rb) do { _Pragma("unroll") \
    for (int mi = 0; mi < 4; ++mi) { \
      const int ro = ((rb) + mi * 16 + l15) * 64; \
      a[mi][0] = *(const bf16x8*)((base) + ro + ck0); \
      a[mi][1] = *(const bf16x8*)((base) + ro + ck1); } } while (0)
#define RD_B(base) do { _Pragma("unroll") \
    for (int n = 0; n < 4; ++n) { \
      const int ro = (bro + n * 16 + l15) * 64; \
      b[n][0] = *(const bf16x8*)((base) + ro + ck0); \
      b[n][1] = *(const bf16x8*)((base) + ro + ck1); } } while (0)
#define MM(qm, qn) do { _Pragma("unroll") \
    for (int mi = 0; mi < 4; ++mi) { _Pragma("unroll") \
      for (int ni = 0; ni < 2; ++ni) { \
        f32x4 t_ = acc[(qm) * 4 + mi][(qn) * 2 + ni]; \
        t_ = MFMA16(a[mi][0], b[(qn) * 2 + ni][0], t_); \
        t_ = MFMA16(a[mi][1], b[(qn) * 2 + ni][1], t_); \
        acc[(qm) * 4 + mi][(qn) * 2 + ni] = t_; } } } while (0)
#define PRIO_MM(qm, qn) do { __builtin_amdgcn_s_setprio(1); MM(qm, qn); \
    __builtin_amdgcn_s_setprio(0); } while (0)

  // prologue: tile0 (B0,B1,A0,A1 @ K-byte 0) + tile1 (B2,B3,A2 @ K-byte 128)
  STG(B0S, sB0, sB1, 0);
  STG(B1S, sB0, sB1, hst);
  STG(A0S, sA0, sA1, 0);
  STG(A1S, sA0, sA1, hst);
  STG(B2S, sB0, sB1, 128);
  STG(B3S, sB0, sB1, 128 + hst);
  STG(A2S, sA0, sA1, 128);
  asm volatile("s_waitcnt vmcnt(6)" ::: "memory");
  BARRIER();

  size_t g = 0;  // K-byte offset of the current even tile
  for (int ktp = 0; ktp < nkt / 2 - 1; ++ktp) {
    // ======== tile even (kt = 2*ktp, K-byte g; slots A0/A1, B0/B1) ========
    RD_A(Ae, 0); RD_B(Be);
    STG(A3S, sA0, sA1, g + 128 + hst);        // tile kt+1, A half1
    asm volatile("s_waitcnt lgkmcnt(8)" ::: "memory");
    BARRIER();
    PRIO_MM(0, 0);
    BARRIER();
    STG(B0S, sB0, sB1, g + 256);              // tile kt+2, B half0
    BARRIER();
    PRIO_MM(0, 1);
    BARRIER();
    RD_A(Ae, 64);
    STG(B1S, sB0, sB1, g + 256 + hst);        // tile kt+2, B half1
    BARRIER();
    PRIO_MM(1, 0);
    BARRIER();
    STG(A0S, sA0, sA1, g + 256);              // tile kt+2, A half0
    BARRIER();
    PRIO_MM(1, 1);
    asm volatile("s_waitcnt vmcnt(6)" ::: "memory");
    BARRIER();
    // ======== tile odd (kt+1, K-byte g+128; slots A2/A3, B2/B3) ========
    RD_A(Ao, 0); RD_B(Bo);
    STG(A1S, sA0, sA1, g + 256 + hst);        // tile kt+2, A half1
    asm volatile("s_waitcnt lgkmcnt(8)" ::: "memory");
    BARRIER();
    PRIO_MM(0, 0);
    BARRIER();
    STG(B2S, sB0, sB1, g + 384);              // tile kt+3, B half0
    BARRIER();
    PRIO_MM(0, 1);
    BARRIER();
    RD_A(Ao, 64);
    STG(B3S, sB0, sB1, g + 384 + hst);        // tile kt+3, B half1
    BARRIER();
    PRIO_MM(1, 0);
    BARRIER();
    STG(A2S, sA0, sA1, g + 384);              // tile kt+3, A half0
    BARRIER();
    PRIO_MM(1, 1);
    asm volatile("s_waitcnt vmcnt(6)" ::: "memory");
    BARRIER();
    g += 256;
  }
  // ======== tail tile nkt-2 (even, K-byte g) ========
  RD_A(Ae, 0); RD_B(Be);
  STG(A3S, sA0, sA1, g + 128 + hst);          // tile nkt-1, A half1
  BARRIER();
  PRIO_MM(0, 0);
  PRIO_MM(0, 1);
  RD_A(Ae, 64);
  PRIO_MM(1, 0);
  PRIO_MM(1, 1);
  asm volatile("s_waitcnt vmcnt(0)" ::: "memory");
  BARRIER();
  // ======== tail tile nkt-1 (odd) ========
  RD_A(Ao, 0); RD_B(Bo);
  PRIO_MM(0, 0);
  PRIO_MM(0, 1);
  RD_A(Ao, 64);
  PRIO_MM(1, 0);
  PRIO_MM(1, 1);

  // epilogue: write (partial) C
  CT* Cp = C + (size_t)ks * M * N;
#pragma unroll
  for (int m = 0; m < 8; ++m) {
    const int row0 = bm * 256 + wr * 128 + m * 16 + 4 * lhi;
#pragma unroll
    for (int n = 0; n < 4; ++n) {
      const int col = bn * 256 + wc * 64 + n * 16 + l15;
#pragma unroll
      for (int i = 0; i < 4; ++i)
        Cp[(size_t)(row0 + i) * N + col] = (CT)acc[m][n][i];
    }
  }
#undef STG
#undef RD_A
#undef RD_B
#undef MM
#undef PRIO_MM
}

// ---------------- RMSNorm + RoPE + bf16 pack of Q/K/V (sums split-K partials) ----------------
__global__ __launch_bounds__(256) void k_norm_rope(
    const bf16_t* __restrict__ qkvA, const bf16_t* __restrict__ qkvB,
    const int* __restrict__ pos,
    const float* __restrict__ qw, const float* __restrict__ kw,
    bf16_t* __restrict__ Q, bf16_t* __restrict__ Kk, bf16_t* __restrict__ V) {
  const int w = blockIdx.x * 4 + (threadIdx.x >> 6);
  const int lane = threadIdx.x & 63;
  const int n = w / 48, slot = w % 48;
  const bf16_t* rowA = qkvA + (size_t)n * 6144;
  const bf16_t* rowB = qkvB + (size_t)n * 6144;
  if (slot >= 40) {
    const int h2 = slot - 40;
    const int c = 5120 + h2 * 128 + lane;
    float x0 = (float)rowA[c] + (float)rowB[c];
    float x1 = (float)rowA[c + 64] + (float)rowB[c + 64];
    bf16_t* dst = V + ((size_t)n * 8 + h2) * 128;
    dst[lane] = (bf16_t)x0;
    dst[lane + 64] = (bf16_t)x1;
    return;
  }
  const bool isq = slot < 32;
  const int h = isq ? slot : slot - 32;
  const int coff = (isq ? h * 128 : 4096 + h * 128) + lane;
  float x0 = (float)rowA[coff] + (float)rowB[coff];
  float x1 = (float)rowA[coff + 64] + (float)rowB[coff + 64];
  float ss = x0 * x0 + x1 * x1;
#pragma unroll
  for (int m = 32; m; m >>= 1) ss += __shfl_xor(ss, m, 64);
  const float inv = rsqrtf(ss * (1.0f / 128.0f) + 1e-6f);
  const float* wgt = isq ? qw : kw;
  float y0 = x0 * inv * wgt[lane];
  float y1 = x1 * inv * wgt[lane + 64];
  const float ang = (float)pos[n] * expf((float)lane * -0.14391156608f);
  float sn, cs;
  sincosf(ang, &sn, &cs);
  float o0 = y0 * cs - y1 * sn;
  float o1 = y1 * cs + y0 * sn;
  bf16_t* dst = isq ? (Q + ((size_t)n * 32 + h) * 128) : (Kk + ((size_t)n * 8 + h) * 128);
  dst[lane] = (bf16_t)o0;
  dst[lane + 64] = (bf16_t)o1;
}

// ---------------- causal GQA flash attention ----------------
__global__ __launch_bounds__(256, 2) void k_attn(
    const bf16_t* __restrict__ Q, const bf16_t* __restrict__ Kk,
    const bf16_t* __restrict__ V, bf16_t* __restrict__ O) {
  __shared__ __align__(16) bf16_t Ks[64 * 128];
  __shared__ __align__(16) bf16_t Vt[128 * 72];
  __shared__ __align__(16) bf16_t Ps[4][32 * 72];
  const int b = blockIdx.x;
  const int qb = b & 7, h = (b >> 3) & 31, s = b >> 8;
  const int kvh = h >> 2;
  const int tid = threadIdx.x, lane = tid & 63, wid = tid >> 6;
  const int l15 = lane & 15, lhi = lane >> 4;

  bf16x8 qf[2][4];
  {
    const int qrow = qb * 128 + wid * 32;
#pragma unroll
    for (int mt = 0; mt < 2; mt++) {
      const size_t base = ((size_t)(s * 1024 + qrow + mt * 16 + l15) * 32 + h) * 128;
#pragma unroll
      for (int kc = 0; kc < 4; kc++)
        qf[mt][kc] = *(const bf16x8*)(Q + base + kc * 32 + 8 * lhi);
    }
  }
  f32x4 of[2][8] = {};
  float mx[2][4], li[2][4];
#pragma unroll
  for (int mt = 0; mt < 2; mt++)
#pragma unroll
    for (int i = 0; i < 4; i++) { mx[mt][i] = -1e30f; li[mt][i] = 0.f; }

  const int ktiles = (qb + 1) * 2;
  const int vr_base = tid >> 4;
  const int vd0 = (tid & 15) * 8;

  for (int kt = 0; kt < ktiles; kt++) {
    const int kv0 = kt * 64;
#pragma unroll
    for (int c = 0; c < 4; c++) {
      const int wb = wid * 4096 + c * 1024;
      const int o = wb + lane * 16;
      const int krow = o >> 8;
      const int ci = (o >> 4) & 15;
      const int cs = ci ^ (krow & 7);
      const char* src =
          (const char*)(Kk + ((size_t)(s * 1024 + kv0 + krow) * 8 + kvh) * 128) + cs * 16;
      gload_lds16(src, (char*)Ks + wb);
    }
#pragma unroll
    for (int c = 0; c < 4; c++) {
      const int r = c * 16 + vr_base;
      bf16x8 v = *(const bf16x8*)(V + ((size_t)(s * 1024 + kv0 + r) * 8 + kvh) * 128 + vd0);
#pragma unroll
      for (int j = 0; j < 8; j++) {
        const int d = vd0 + j;
        const int cc = (r >> 3) ^ ((d >> 3) & 7);
        Vt[d * 72 + cc * 8 + (r & 7)] = v[j];
      }
    }
    __syncthreads();

    f32x4 sf[2][4] = {};
#pragma unroll
    for (int kc = 0; kc < 4; kc++) {
      bf16x8 kf[4];
#pragma unroll
      for (int n = 0; n < 4; n++) {
        const int krow = n * 16 + l15;
        const int ci = (kc * 4 + lhi) ^ (krow & 7);
        kf[n] = *(const bf16x8*)(Ks + krow * 128 + ci * 8);
      }
#pragma unroll
      for (int mt = 0; mt < 2; mt++)
#pragma unroll
        for (int n = 0; n < 4; n++)
          sf[mt][n] = MFMA16(qf[mt][kc], kf[n], sf[mt][n]);
    }

    const bool masked = (kt >= 2 * qb);
    const float scale = 0.08838834764831845f;
    float pv[2][4][4];
#pragma unroll
    for (int mt = 0; mt < 2; mt++) {
#pragma unroll
      for (int i = 0; i < 4; i++) {
        float rm = -1e30f;
#pragma unroll
        for (int n = 0; n < 4; n++) {
          float sv = sf[mt][n][i] * scale;
          if (masked) {
            const int kvg = kv0 + n * 16 + l15;
            const int qg = qb * 128 + wid * 32 + mt * 16 + 4 * lhi + i;
            if (kvg > qg) sv = -1e30f;
          }
          pv[mt][n][i] = sv;
          rm = fmaxf(rm, sv);
        }
#pragma unroll
        for (int mm = 1; mm < 16; mm <<= 1) rm = fmaxf(rm, __shfl_xor(rm, mm, 64));
        const float nm = fmaxf(mx[mt][i], rm);
        float ts = 0.f;
#pragma unroll
        for (int n = 0; n < 4; n++) {
          float e = __expf(pv[mt][n][i] - nm);
          pv[mt][n][i] = e;
          ts += e;
        }
#pragma unroll
        for (int mm = 1; mm < 16; mm <<= 1) ts += __shfl_xor(ts, mm, 64);
        const float al = __expf(mx[mt][i] - nm);
        li[mt][i] = li[mt][i] * al + ts;
        mx[mt][i] = nm;
#pragma unroll
        for (int n = 0; n < 8; n++) of[mt][n][i] *= al;
      }
    }

    bf16_t* myP = &Ps[wid][0];
#pragma unroll
    for (int mt = 0; mt < 2; mt++)
#pragma unroll
      for (int n = 0; n < 4; n++)
#pragma unroll
        for (int i = 0; i < 4; i++)
          myP[(mt * 16 + 4 * lhi + i) * 72 + n * 16 + l15] = (bf16_t)pv[mt][n][i];

#pragma unroll
    for (int kc = 0; kc < 2; kc++) {
      bf16x8 pf[2];
#pragma unroll
      for (int mt = 0; mt < 2; mt++)
        pf[mt] = *(const bf16x8*)(myP + (mt * 16 + l15) * 72 + kc * 32 + 8 * lhi);
#pragma unroll
      for (int n = 0; n < 8; n++) {
        const int d = n * 16 + l15;
        const int cc = (kc * 4 + lhi) ^ ((d >> 3) & 7);
        bf16x8 vf = *(const bf16x8*)(Vt + d * 72 + cc * 8);
#pragma unroll
        for (int mt = 0; mt < 2; mt++)
          of[mt][n] = MFMA16(pf[mt], vf, of[mt][n]);
      }
    }
    __syncthreads();
  }

#pragma unroll
  for (int mt = 0; mt < 2; mt++) {
#pragma unroll
    for (int i = 0; i < 4; i++) {
      const float invl = 1.0f / li[mt][i];
      const int tokrow = qb * 128 + wid * 32 + mt * 16 + 4 * lhi + i;
      bf16_t* dst = O + (size_t)(s * 1024 + tokrow) * 4096 + h * 128;
#pragma unroll
      for (int n = 0; n < 8; n++)
        dst[n * 16 + l15] = (bf16_t)(of[mt][n][i] * invl);
    }
  }
}

// ---------------- launch ----------------
extern "C" void kernel_launch(void* const* d_in, const int* in_sizes, int n_in,
                              void* d_out, int out_size, void* d_ws, size_t ws_size,
                              hipStream_t stream) {
  const float* hidden = (const float*)d_in[0];
  const float* mu     = (const float*)d_in[1];
  const int*   pos    = (const int*)d_in[2];
  const float* Wq  = (const float*)d_in[3];
  const float* Wk  = (const float*)d_in[4];
  const float* Wv  = (const float*)d_in[5];
  const float* Wo  = (const float*)d_in[6];
  const float* Wmq = (const float*)d_in[7];
  const float* Wmk = (const float*)d_in[8];
  const float* Wmv = (const float*)d_in[9];
  const float* qw  = (const float*)d_in[10];
  const float* kw  = (const float*)d_in[11];
  float* out = (float*)d_out;
  char* ws = (char*)d_ws;

  if (ws_size < 301989888u) return;  // need 288 MiB

  bf16_t* Wqkv = (bf16_t*)(ws);                    // [6144][8192] bf16   0..96MiB
  bf16_t* Wob  = (bf16_t*)(ws + 100663296);        // [4096][4096] bf16   96..128MiB
  bf16_t* Xb   = (bf16_t*)(ws + 134217728);        // [4096][8192] bf16   128..192MiB
  bf16_t* Qb   = (bf16_t*)(ws + 134217728);        // aliases Xb (dead after GEMM1) 32MiB
  bf16_t* Kb   = (bf16_t*)(ws + 167772160);        // 8MiB
  bf16_t* Vb   = (bf16_t*)(ws + 176160768);        // 8MiB
  bf16_t* qkvA = (bf16_t*)(ws + 201326592);        // [4096][6144] bf16 partial ks=0 (48MiB)
  bf16_t* qkvB = (bf16_t*)(ws + 251658240);        // partial ks=1 (48MiB), contiguous after A
  bf16_t* Ob   = (bf16_t*)(ws + 201326592);        // aliases qkvA (dead after norm/rope) 32MiB

  k_pack_all<<<2048, 256, 0, stream>>>(hidden, mu, Wq, Wmq, Wk, Wmk, Wv, Wmv, Wo,
                                       Xb, Wqkv, Wob);
  k_gemm256<bf16_t, 2><<<768, 512, 0, stream>>>(Xb, Wqkv, qkvA, 4096, 6144, 8192);
  k_norm_rope<<<49152, 256, 0, stream>>>(qkvA, qkvB, pos, qw, kw, Qb, Kb, Vb);
  k_attn<<<1024, 256, 0, stream>>>(Qb, Kb, Vb, Ob);
  k_gemm256<float, 1><<<256, 512, 0, stream>>>(Ob, Wob, out, 4096, 4096, 4096);
}

// Round 6
// 781.259 us; speedup vs baseline: 1.2400x; 1.0028x over previous
//
#include <hip/hip_runtime.h>
#include <hip/hip_bf16.h>
#include <stdint.h>

#define DEV static __device__ __forceinline__

typedef __bf16 bf16_t;
typedef __bf16 bf16x8 __attribute__((ext_vector_type(8)));
typedef __bf16 bf16x4 __attribute__((ext_vector_type(4)));
typedef float  f32x4  __attribute__((ext_vector_type(4)));

// H=32 q heads, KV=8 kv heads, D=128, HID=4096, S=4, L=1024, N=4096

DEV void gload_lds16(const void* g, void* l) {
  __builtin_amdgcn_global_load_lds(
      (__attribute__((address_space(1))) void*)(uintptr_t)(g),
      (__attribute__((address_space(3))) void*)(uintptr_t)(l),
      16, 0, 0);
}

#define BARRIER() asm volatile("s_barrier" ::: "memory")
#define MFMA16(a, b, c) __builtin_amdgcn_mfma_f32_16x16x32_bf16((a), (b), (c), 0, 0, 0)

// ---------------- unified pack/convert kernel ----------------
DEV void pack_pair_chunk(const float* __restrict__ A, const float* __restrict__ B,
                         bf16_t* __restrict__ dst, size_t i) {
  size_t r = i >> 10, c = i & 1023;
  float4 va = ((const float4*)A)[i];
  float4 vb = ((const float4*)B)[i];
  bf16x4 oa = {(bf16_t)va.x, (bf16_t)va.y, (bf16_t)va.z, (bf16_t)va.w};
  bf16x4 ob = {(bf16_t)vb.x, (bf16_t)vb.y, (bf16_t)vb.z, (bf16_t)vb.w};
  ((bf16x4*)dst)[r * 2048 + c] = oa;
  ((bf16x4*)dst)[r * 2048 + 1024 + c] = ob;
}

__global__ void k_pack_all(const float* __restrict__ hidden, const float* __restrict__ mu,
                           const float* __restrict__ Wq, const float* __restrict__ Wmq,
                           const float* __restrict__ Wk, const float* __restrict__ Wmk,
                           const float* __restrict__ Wv, const float* __restrict__ Wmv,
                           const float* __restrict__ Wo,
                           bf16_t* __restrict__ Xb, bf16_t* __restrict__ Wqkv,
                           bf16_t* __restrict__ Wob) {
  const size_t t0 = 4194304, t1 = 8388608, t2 = 9437184, t3 = 10485760, t4 = 14680064;
  size_t stride = (size_t)gridDim.x * blockDim.x;
  for (size_t i = (size_t)blockIdx.x * blockDim.x + threadIdx.x; i < t4; i += stride) {
    if (i < t0) {
      pack_pair_chunk(hidden, mu, Xb, i);
    } else if (i < t1) {
      pack_pair_chunk(Wq, Wmq, Wqkv, i - t0);
    } else if (i < t2) {
      pack_pair_chunk(Wk, Wmk, Wqkv + (size_t)4096 * 8192, i - t1);
    } else if (i < t3) {
      pack_pair_chunk(Wv, Wmv, Wqkv + (size_t)5120 * 8192, i - t2);
    } else {
      size_t j = i - t3;
      float4 v = ((const float4*)Wo)[j];
      bf16x4 o = {(bf16_t)v.x, (bf16_t)v.y, (bf16_t)v.z, (bf16_t)v.w};
      ((bf16x4*)Wob)[j] = o;
    }
  }
}

// ---------------- 256x256 8-phase bf16 GEMM: C = A[M][K] * B[N][K]^T ----------------
// 512 threads = 8 waves (2M x 4N), BK=64 (= 128 BYTES of K per tile). LDS ring 128 KiB,
// 16B-chunk XOR swizzle (inverse-swizzled global source -> linear LDS dest; swizzled ds_read).
// kt-unrolled x2. Read distribution 12/4/8/0 (fine interleave, m196); stage placement
// 1/0/1/2 chosen so every restage is >=1 closing barrier after the last ds_read of its
// slot (A slots last-read ph2 -> restaged ph3+; B slots last-read ph1 -> restaged ph2+).
// vmcnt(6) once per K-tile; drain 0 only at the tail. bm-fast tile order for L2 sharing.
template<typename CT, int NSPLIT>
__global__ __launch_bounds__(512, 2) void k_gemm256(
    const bf16_t* __restrict__ A, const bf16_t* __restrict__ B,
    CT* __restrict__ C, int M, int N, int Kfull) {
  __shared__ __align__(16) char lds[131072];
  const int tid = threadIdx.x, lane = tid & 63, wid = tid >> 6;
  const int l15 = lane & 15, lhi = lane >> 4;
  const int wr = wid >> 2, wc = wid & 3;
  // bijective XCD swizzle (nwg % 8 == 0 for all our launches)
  const int bid = blockIdx.x, nwg = gridDim.x;
  const int cpx = nwg >> 3;
  const int swz = (bid & 7) * cpx + (bid >> 3);
  const int nbm = M >> 8;
  const int tiles = nbm * (N >> 8);
  const int ks = (NSPLIT > 1) ? (swz / tiles) : 0;
  const int t  = (NSPLIT > 1) ? (swz % tiles) : swz;
  const int bm = t % nbm, bn = t / nbm;   // bm-fast
  const int Kloop = Kfull / NSPLIT;
  const int nkt = Kloop >> 6;

  const size_t rowK = (size_t)Kfull * 2;
  const size_t kbase = (size_t)ks * Kloop * 2;
  const int off0 = wid * 1024 + lane * 16, off1 = off0 + 8192;
  const int r0 = off0 >> 7, r1 = off1 >> 7;
  const int c0 = ((off0 >> 4) & 7) ^ (r0 & 7);
  const int c1 = ((off1 >> 4) & 7) ^ (r1 & 7);
  const char* sA0 = (const char*)A + ((size_t)bm * 256 + r0) * rowK + kbase + c0 * 16;
  const char* sA1 = (const char*)A + ((size_t)bm * 256 + r1) * rowK + kbase + c1 * 16;
  const char* sB0 = (const char*)B + ((size_t)bn * 256 + r0) * rowK + kbase + c0 * 16;
  const char* sB1 = (const char*)B + ((size_t)bn * 256 + r1) * rowK + kbase + c1 * 16;
  const size_t hst = (size_t)128 * rowK;

  enum { A0S = 0, A1S = 16384, A2S = 32768, A3S = 49152,
         B0S = 65536, B1S = 81920, B2S = 98304, B3S = 114688 };

#define STG(slot, pa, pb, off) do { \
    gload_lds16((pa) + (off), lds + (slot) + wid * 1024); \
    gload_lds16((pb) + (off), lds + (slot) + 8192 + wid * 1024); } while (0)

  const bf16_t* Ae = (const bf16_t*)(lds + A0S + wr * 16384);
  const bf16_t* Be = (const bf16_t*)(lds + B0S + (wc >> 1) * 16384);
  const bf16_t* Ao = (const bf16_t*)(lds + A2S + wr * 16384);
  const bf16_t* Bo = (const bf16_t*)(lds + B2S + (wc >> 1) * 16384);
  const int bro = (wc & 1) * 64;

  f32x4 acc[8][4] = {};
  bf16x8 a[4][2], b[4][2];
  const int xr = l15 & 7;
  const int ck0 = (lhi ^ xr) * 8;
  const int ck1 = ((4 + lhi) ^ xr) * 8;

#define RD_A(base, rb) do { _Pragma("unroll") \
    for (int mi = 0; mi < 4; ++mi) { \
      const int ro = ((rb) + mi * 16 + l15) * 64; \
      a[mi][0] = *(const bf16x8*)((base) + ro + ck0); \
      a[mi][1] = *(const bf16x8*)((base) + ro + ck1); } } while (0)
#define RD_B2(base, n0) do { _Pragma("unroll") \
    for (int n = (n0); n < (n0) + 2; ++n) { \
      const int ro = (bro + n * 16 + l15) * 64; \
      b[n][0] = *(const bf16x8*)((base) + ro + ck0); \
      b[n][1] = *(const bf16x8*)((base) + ro + ck1); } } while (0)
#define MM(qm, qn) do { _Pragma("unroll") \
    for (int mi = 0; mi < 4; ++mi) { _Pragma("unroll") \
      for (int ni = 0; ni < 2; ++ni) { \
        f32x4 t_ = acc[(qm) * 4 + mi][(qn) * 2 + ni]; \
        t_ = MFMA16(a[mi][0], b[(qn) * 2 + ni][0], t_); \
        t_ = MFMA16(a[mi][1], b[(qn) * 2 + ni][1], t_); \
        acc[(qm) * 4 + mi][(qn) * 2 + ni] = t_; } } } while (0)
#define PRIO_MM(qm, qn) do { __builtin_amdgcn_s_setprio(1); MM(qm, qn); \
    __builtin_amdgcn_s_setprio(0); } while (0)

  // prologue: tile0 (B0,B1,A0,A1 @ K-byte 0) + tile1 (B2,B3,A2 @ K-byte 128)
  STG(B0S, sB0, sB1, 0);
  STG(B1S, sB0, sB1, hst);
  STG(A0S, sA0, sA1, 0);
  STG(A1S, sA0, sA1, hst);
  STG(B2S, sB0, sB1, 128);
  STG(B3S, sB0, sB1, 128 + hst);
  STG(A2S, sA0, sA1, 128);
  asm volatile("s_waitcnt vmcnt(6)" ::: "memory");
  BARRIER();

  size_t g = 0;  // K-byte offset of the current even tile
  for (int ktp = 0; ktp < nkt / 2 - 1; ++ktp) {
    // ======== tile even (kt = 2*ktp, K-byte g; slots A0/A1, B0/B1) ========
    RD_A(Ae, 0); RD_B2(Be, 0);                // 12 reads for MM(0,0)
    STG(A3S, sA0, sA1, g + 128 + hst);        // tile kt+1, A half1
    BARRIER();
    PRIO_MM(0, 0);
    BARRIER();
    RD_B2(Be, 2);                             // 4 reads for MM(0,1)
    BARRIER();
    PRIO_MM(0, 1);
    BARRIER();
    RD_A(Ae, 64);                             // 8 reads for MM(1,*)
    STG(B0S, sB0, sB1, g + 256);              // tile kt+2, B half0
    BARRIER();
    PRIO_MM(1, 0);
    BARRIER();
    STG(B1S, sB0, sB1, g + 256 + hst);        // tile kt+2, B half1
    STG(A0S, sA0, sA1, g + 256);              // tile kt+2, A half0
    BARRIER();
    PRIO_MM(1, 1);
    asm volatile("s_waitcnt vmcnt(6)" ::: "memory");
    BARRIER();
    // ======== tile odd (kt+1, K-byte g+128; slots A2/A3, B2/B3) ========
    RD_A(Ao, 0); RD_B2(Bo, 0);
    STG(A1S, sA0, sA1, g + 256 + hst);        // tile kt+2, A half1
    BARRIER();
    PRIO_MM(0, 0);
    BARRIER();
    RD_B2(Bo, 2);
    BARRIER();
    PRIO_MM(0, 1);
    BARRIER();
    RD_A(Ao, 64);
    STG(B2S, sB0, sB1, g + 384);              // tile kt+3, B half0
    BARRIER();
    PRIO_MM(1, 0);
    BARRIER();
    STG(B3S, sB0, sB1, g + 384 + hst);        // tile kt+3, B half1
    STG(A2S, sA0, sA1, g + 384);              // tile kt+3, A half0
    BARRIER();
    PRIO_MM(1, 1);
    asm volatile("s_waitcnt vmcnt(6)" ::: "memory");
    BARRIER();
    g += 256;
  }
  // ======== tail tile nkt-2 (even, K-byte g) ========
  RD_A(Ae, 0); RD_B2(Be, 0); RD_B2(Be, 2);
  STG(A3S, sA0, sA1, g + 128 + hst);          // tile nkt-1, A half1
  BARRIER();
  PRIO_MM(0, 0);
  PRIO_MM(0, 1);
  RD_A(Ae, 64);
  PRIO_MM(1, 0);
  PRIO_MM(1, 1);
  asm volatile("s_waitcnt vmcnt(0)" ::: "memory");
  BARRIER();
  // ======== tail tile nkt-1 (odd) ========
  RD_A(Ao, 0); RD_B2(Bo, 0); RD_B2(Bo, 2);
  PRIO_MM(0, 0);
  PRIO_MM(0, 1);
  RD_A(Ao, 64);
  PRIO_MM(1, 0);
  PRIO_MM(1, 1);

  // epilogue: write (partial) C
  CT* Cp = C + (size_t)ks * M * N;
#pragma unroll
  for (int m = 0; m < 8; ++m) {
    const int row0 = bm * 256 + wr * 128 + m * 16 + 4 * lhi;
#pragma unroll
    for (int n = 0; n < 4; ++n) {
      const int col = bn * 256 + wc * 64 + n * 16 + l15;
#pragma unroll
      for (int i = 0; i < 4; ++i)
        Cp[(size_t)(row0 + i) * N + col] = (CT)acc[m][n][i];
    }
  }
#undef STG
#undef RD_A
#undef RD_B2
#undef MM
#undef PRIO_MM
}

// ---------------- RMSNorm + RoPE + bf16 pack of Q/K/V (sums split-K partials) ----------------
__global__ __launch_bounds__(256) void k_norm_rope(
    const bf16_t* __restrict__ qkvA, const bf16_t* __restrict__ qkvB,
    const int* __restrict__ pos,
    const float* __restrict__ qw, const float* __restrict__ kw,
    bf16_t* __restrict__ Q, bf16_t* __restrict__ Kk, bf16_t* __restrict__ V) {
  const int w = blockIdx.x * 4 + (threadIdx.x >> 6);
  const int lane = threadIdx.x & 63;
  const int n = w / 48, slot = w % 48;
  const bf16_t* rowA = qkvA + (size_t)n * 6144;
  const bf16_t* rowB = qkvB + (size_t)n * 6144;
  if (slot >= 40) {
    const int h2 = slot - 40;
    const int c = 5120 + h2 * 128 + lane;
    float x0 = (float)rowA[c] + (float)rowB[c];
    float x1 = (float)rowA[c + 64] + (float)rowB[c + 64];
    bf16_t* dst = V + ((size_t)n * 8 + h2) * 128;
    dst[lane] = (bf16_t)x0;
    dst[lane + 64] = (bf16_t)x1;
    return;
  }
  const bool isq = slot < 32;
  const int h = isq ? slot : slot - 32;
  const int coff = (isq ? h * 128 : 4096 + h * 128) + lane;
  float x0 = (float)rowA[coff] + (float)rowB[coff];
  float x1 = (float)rowA[coff + 64] + (float)rowB[coff + 64];
  float ss = x0 * x0 + x1 * x1;
#pragma unroll
  for (int m = 32; m; m >>= 1) ss += __shfl_xor(ss, m, 64);
  const float inv = rsqrtf(ss * (1.0f / 128.0f) + 1e-6f);
  const float* wgt = isq ? qw : kw;
  float y0 = x0 * inv * wgt[lane];
  float y1 = x1 * inv * wgt[lane + 64];
  const float ang = (float)pos[n] * expf((float)lane * -0.14391156608f);
  float sn, cs;
  sincosf(ang, &sn, &cs);
  float o0 = y0 * cs - y1 * sn;
  float o1 = y1 * cs + y0 * sn;
  bf16_t* dst = isq ? (Q + ((size_t)n * 32 + h) * 128) : (Kk + ((size_t)n * 8 + h) * 128);
  dst[lane] = (bf16_t)o0;
  dst[lane + 64] = (bf16_t)o1;
}

// ---------------- causal GQA flash attention ----------------
// Block remap (assumes round-robin blockIdx -> XCD): x=b&7, y=b>>3;
// h = 4x + ((y>>3)&3)  -> each XCD owns exactly one kv head (2 MB KV set, L2-fits);
// qb = 7 - (y&7)       -> balanced causal work per XCD, heavy-first drain;
// s = y >> 5. Bijective over the 1024-block grid.
__global__ __launch_bounds__(256, 2) void k_attn(
    const bf16_t* __restrict__ Q, const bf16_t* __restrict__ Kk,
    const bf16_t* __restrict__ V, bf16_t* __restrict__ O) {
  __shared__ __align__(16) bf16_t Ks[64 * 128];
  __shared__ __align__(16) bf16_t Vt[128 * 72];
  __shared__ __align__(16) bf16_t Ps[4][32 * 72];
  const int b = blockIdx.x;
  const int x = b & 7, y = b >> 3;
  const int h = x * 4 + ((y >> 3) & 3);
  const int qb = 7 - (y & 7);
  const int s = y >> 5;
  const int kvh = h >> 2;
  const int tid = threadIdx.x, lane = tid & 63, wid = tid >> 6;
  const int l15 = lane & 15, lhi = lane >> 4;

  bf16x8 qf[2][4];
  {
    const int qrow = qb * 128 + wid * 32;
#pragma unroll
    for (int mt = 0; mt < 2; mt++) {
      const size_t base = ((size_t)(s * 1024 + qrow + mt * 16 + l15) * 32 + h) * 128;
#pragma unroll
      for (int kc = 0; kc < 4; kc++)
        qf[mt][kc] = *(const bf16x8*)(Q + base + kc * 32 + 8 * lhi);
    }
  }
  f32x4 of[2][8] = {};
  float mx[2][4], li[2][4];
#pragma unroll
  for (int mt = 0; mt < 2; mt++)
#pragma unroll
    for (int i = 0; i < 4; i++) { mx[mt][i] = -1e30f; li[mt][i] = 0.f; }

  const int ktiles = (qb + 1) * 2;
  const int vr_base = tid >> 4;
  const int vd0 = (tid & 15) * 8;

  for (int kt = 0; kt < ktiles; kt++) {
    const int kv0 = kt * 64;
#pragma unroll
    for (int c = 0; c < 4; c++) {
      const int wb = wid * 4096 + c * 1024;
      const int o = wb + lane * 16;
      const int krow = o >> 8;
      const int ci = (o >> 4) & 15;
      const int cs = ci ^ (krow & 7);
      const char* src =
          (const char*)(Kk + ((size_t)(s * 1024 + kv0 + krow) * 8 + kvh) * 128) + cs * 16;
      gload_lds16(src, (char*)Ks + wb);
    }
#pragma unroll
    for (int c = 0; c < 4; c++) {
      const int r = c * 16 + vr_base;
      bf16x8 v = *(const bf16x8*)(V + ((size_t)(s * 1024 + kv0 + r) * 8 + kvh) * 128 + vd0);
#pragma unroll
      for (int j = 0; j < 8; j++) {
        const int d = vd0 + j;
        const int cc = (r >> 3) ^ ((d >> 3) & 7);
        Vt[d * 72 + cc * 8 + (r & 7)] = v[j];
      }
    }
    __syncthreads();

    f32x4 sf[2][4] = {};
#pragma unroll
    for (int kc = 0; kc < 4; kc++) {
      bf16x8 kf[4];
#pragma unroll
      for (int n = 0; n < 4; n++) {
        const int krow = n * 16 + l15;
        const int ci = (kc * 4 + lhi) ^ (krow & 7);
        kf[n] = *(const bf16x8*)(Ks + krow * 128 + ci * 8);
      }
#pragma unroll
      for (int mt = 0; mt < 2; mt++)
#pragma unroll
        for (int n = 0; n < 4; n++)
          sf[mt][n] = MFMA16(qf[mt][kc], kf[n], sf[mt][n]);
    }

    const bool masked = (kt >= 2 * qb);
    const float scale = 0.08838834764831845f;
    float pv[2][4][4];
#pragma unroll
    for (int mt = 0; mt < 2; mt++) {
#pragma unroll
      for (int i = 0; i < 4; i++) {
        float rm = -1e30f;
#pragma unroll
        for (int n = 0; n < 4; n++) {
          float sv = sf[mt][n][i] * scale;
          if (masked) {
            const int kvg = kv0 + n * 16 + l15;
            const int qg = qb * 128 + wid * 32 + mt * 16 + 4 * lhi + i;
            if (kvg > qg) sv = -1e30f;
          }
          pv[mt][n][i] = sv;
          rm = fmaxf(rm, sv);
        }
#pragma unroll
        for (int mm = 1; mm < 16; mm <<= 1) rm = fmaxf(rm, __shfl_xor(rm, mm, 64));
        const float nm = fmaxf(mx[mt][i], rm);
        float ts = 0.f;
#pragma unroll
        for (int n = 0; n < 4; n++) {
          float e = __expf(pv[mt][n][i] - nm);
          pv[mt][n][i] = e;
          ts += e;
        }
#pragma unroll
        for (int mm = 1; mm < 16; mm <<= 1) ts += __shfl_xor(ts, mm, 64);
        const float al = __expf(mx[mt][i] - nm);
        li[mt][i] = li[mt][i] * al + ts;
        mx[mt][i] = nm;
#pragma unroll
        for (int n = 0; n < 8; n++) of[mt][n][i] *= al;
      }
    }

    bf16_t* myP = &Ps[wid][0];
#pragma unroll
    for (int mt = 0; mt < 2; mt++)
#pragma unroll
      for (int n = 0; n < 4; n++)
#pragma unroll
        for (int i = 0; i < 4; i++)
          myP[(mt * 16 + 4 * lhi + i) * 72 + n * 16 + l15] = (bf16_t)pv[mt][n][i];

#pragma unroll
    for (int kc = 0; kc < 2; kc++) {
      bf16x8 pf[2];
#pragma unroll
      for (int mt = 0; mt < 2; mt++)
        pf[mt] = *(const bf16x8*)(myP + (mt * 16 + l15) * 72 + kc * 32 + 8 * lhi);
#pragma unroll
      for (int n = 0; n < 8; n++) {
        const int d = n * 16 + l15;
        const int cc = (kc * 4 + lhi) ^ ((d >> 3) & 7);
        bf16x8 vf = *(const bf16x8*)(Vt + d * 72 + cc * 8);
#pragma unroll
        for (int mt = 0; mt < 2; mt++)
          of[mt][n] = MFMA16(pf[mt], vf, of[mt][n]);
      }
    }
    __syncthreads();
  }

#pragma unroll
  for (int mt = 0; mt < 2; mt++) {
#pragma unroll
    for (int i = 0; i < 4; i++) {
      const float invl = 1.0f / li[mt][i];
      const int tokrow = qb * 128 + wid * 32 + mt * 16 + 4 * lhi + i;
      bf16_t* dst = O + (size_t)(s * 1024 + tokrow) * 4096 + h * 128;
#pragma unroll
      for (int n = 0; n < 8; n++)
        dst[n * 16 + l15] = (bf16_t)(of[mt][n][i] * invl);
    }
  }
}

// ---------------- launch ----------------
extern "C" void kernel_launch(void* const* d_in, const int* in_sizes, int n_in,
                              void* d_out, int out_size, void* d_ws, size_t ws_size,
                              hipStream_t stream) {
  const float* hidden = (const float*)d_in[0];
  const float* mu     = (const float*)d_in[1];
  const int*   pos    = (const int*)d_in[2];
  const float* Wq  = (const float*)d_in[3];
  const float* Wk  = (const float*)d_in[4];
  const float* Wv  = (const float*)d_in[5];
  const float* Wo  = (const float*)d_in[6];
  const float* Wmq = (const float*)d_in[7];
  const float* Wmk = (const float*)d_in[8];
  const float* Wmv = (const float*)d_in[9];
  const float* qw  = (const float*)d_in[10];
  const float* kw  = (const float*)d_in[11];
  float* out = (float*)d_out;
  char* ws = (char*)d_ws;

  if (ws_size < 301989888u) return;  // need 288 MiB

  bf16_t* Wqkv = (bf16_t*)(ws);                    // [6144][8192] bf16   0..96MiB
  bf16_t* Wob  = (bf16_t*)(ws + 100663296);        // [4096][4096] bf16   96..128MiB
  bf16_t* Xb   = (bf16_t*)(ws + 134217728);        // [4096][8192] bf16   128..192MiB
  bf16_t* Qb   = (bf16_t*)(ws + 134217728);        // aliases Xb (dead after GEMM1) 32MiB
  bf16_t* Kb   = (bf16_t*)(ws + 167772160);        // 8MiB
  bf16_t* Vb   = (bf16_t*)(ws + 176160768);        // 8MiB
  bf16_t* qkvA = (bf16_t*)(ws + 201326592);        // [4096][6144] bf16 partial ks=0 (48MiB)
  bf16_t* qkvB = (bf16_t*)(ws + 251658240);        // partial ks=1 (48MiB)
  bf16_t* Ob   = (bf16_t*)(ws + 201326592);        // aliases qkvA (dead after norm/rope) 32MiB

  k_pack_all<<<2048, 256, 0, stream>>>(hidden, mu, Wq, Wmq, Wk, Wmk, Wv, Wmv, Wo,
                                       Xb, Wqkv, Wob);
  k_gemm256<bf16_t, 2><<<768, 512, 0, stream>>>(Xb, Wqkv, qkvA, 4096, 6144, 8192);
  k_norm_rope<<<49152, 256, 0, stream>>>(qkvA, qkvB, pos, qw, kw, Qb, Kb, Vb);
  k_attn<<<1024, 256, 0, stream>>>(Qb, Kb, Vb, Ob);
  k_gemm256<float, 1><<<256, 512, 0, stream>>>(Ob, Wob, out, 4096, 4096, 4096);
}

// Round 7
// 768.474 us; speedup vs baseline: 1.2606x; 1.0166x over previous
//
#include <hip/hip_runtime.h>
#include <hip/hip_bf16.h>
#include <stdint.h>

#define DEV static __device__ __forceinline__

typedef __bf16 bf16_t;
typedef __bf16 bf16x8 __attribute__((ext_vector_type(8)));
typedef __bf16 bf16x4 __attribute__((ext_vector_type(4)));
typedef float  f32x4  __attribute__((ext_vector_type(4)));

// H=32 q heads, KV=8 kv heads, D=128, HID=4096, S=4, L=1024, N=4096

DEV void gload_lds16(const void* g, void* l) {
  __builtin_amdgcn_global_load_lds(
      (__attribute__((address_space(1))) void*)(uintptr_t)(g),
      (__attribute__((address_space(3))) void*)(uintptr_t)(l),
      16, 0, 0);
}

#define BARRIER() asm volatile("s_barrier" ::: "memory")
#define MFMA16(a, b, c) __builtin_amdgcn_mfma_f32_16x16x32_bf16((a), (b), (c), 0, 0, 0)

// ---------------- unified pack/convert kernel ----------------
DEV void pack_pair_chunk(const float* __restrict__ A, const float* __restrict__ B,
                         bf16_t* __restrict__ dst, size_t i) {
  size_t r = i >> 10, c = i & 1023;
  float4 va = ((const float4*)A)[i];
  float4 vb = ((const float4*)B)[i];
  bf16x4 oa = {(bf16_t)va.x, (bf16_t)va.y, (bf16_t)va.z, (bf16_t)va.w};
  bf16x4 ob = {(bf16_t)vb.x, (bf16_t)vb.y, (bf16_t)vb.z, (bf16_t)vb.w};
  ((bf16x4*)dst)[r * 2048 + c] = oa;
  ((bf16x4*)dst)[r * 2048 + 1024 + c] = ob;
}

__global__ void k_pack_all(const float* __restrict__ hidden, const float* __restrict__ mu,
                           const float* __restrict__ Wq, const float* __restrict__ Wmq,
                           const float* __restrict__ Wk, const float* __restrict__ Wmk,
                           const float* __restrict__ Wv, const float* __restrict__ Wmv,
                           const float* __restrict__ Wo,
                           bf16_t* __restrict__ Xb, bf16_t* __restrict__ Wqkv,
                           bf16_t* __restrict__ Wob) {
  const size_t t0 = 4194304, t1 = 8388608, t2 = 9437184, t3 = 10485760, t4 = 14680064;
  size_t stride = (size_t)gridDim.x * blockDim.x;
  for (size_t i = (size_t)blockIdx.x * blockDim.x + threadIdx.x; i < t4; i += stride) {
    if (i < t0) {
      pack_pair_chunk(hidden, mu, Xb, i);
    } else if (i < t1) {
      pack_pair_chunk(Wq, Wmq, Wqkv, i - t0);
    } else if (i < t2) {
      pack_pair_chunk(Wk, Wmk, Wqkv + (size_t)4096 * 8192, i - t1);
    } else if (i < t3) {
      pack_pair_chunk(Wv, Wmv, Wqkv + (size_t)5120 * 8192, i - t2);
    } else {
      size_t j = i - t3;
      float4 v = ((const float4*)Wo)[j];
      bf16x4 o = {(bf16_t)v.x, (bf16_t)v.y, (bf16_t)v.z, (bf16_t)v.w};
      ((bf16x4*)Wob)[j] = o;
    }
  }
}

// ---------------- 256x256 8-phase bf16 GEMM (R5 schedule): C = A[M][K] * B[N][K]^T ----
// 512 threads = 8 waves (2M x 4N), BK=64 (=128 K-bytes/tile). LDS ring 128 KiB,
// 16B-chunk XOR swizzle. kt-unrolled x2; read distribution 16/0/8/0 (race-free);
// vmcnt(6) once per K-tile; drain 0 only at tail; bm-fast tile order for L2 sharing.
template<typename CT, int NSPLIT>
__global__ __launch_bounds__(512, 2) void k_gemm256(
    const bf16_t* __restrict__ A, const bf16_t* __restrict__ B,
    CT* __restrict__ C, int M, int N, int Kfull) {
  __shared__ __align__(16) char lds[131072];
  const int tid = threadIdx.x, lane = tid & 63, wid = tid >> 6;
  const int l15 = lane & 15, lhi = lane >> 4;
  const int wr = wid >> 2, wc = wid & 3;
  const int bid = blockIdx.x, nwg = gridDim.x;
  const int cpx = nwg >> 3;
  const int swz = (bid & 7) * cpx + (bid >> 3);
  const int nbm = M >> 8;
  const int tiles = nbm * (N >> 8);
  const int ks = (NSPLIT > 1) ? (swz / tiles) : 0;
  const int t  = (NSPLIT > 1) ? (swz % tiles) : swz;
  const int bm = t % nbm, bn = t / nbm;   // bm-fast
  const int Kloop = Kfull / NSPLIT;
  const int nkt = Kloop >> 6;

  const size_t rowK = (size_t)Kfull * 2;
  const size_t kbase = (size_t)ks * Kloop * 2;
  const int off0 = wid * 1024 + lane * 16, off1 = off0 + 8192;
  const int r0 = off0 >> 7, r1 = off1 >> 7;
  const int c0 = ((off0 >> 4) & 7) ^ (r0 & 7);
  const int c1 = ((off1 >> 4) & 7) ^ (r1 & 7);
  const char* sA0 = (const char*)A + ((size_t)bm * 256 + r0) * rowK + kbase + c0 * 16;
  const char* sA1 = (const char*)A + ((size_t)bm * 256 + r1) * rowK + kbase + c1 * 16;
  const char* sB0 = (const char*)B + ((size_t)bn * 256 + r0) * rowK + kbase + c0 * 16;
  const char* sB1 = (const char*)B + ((size_t)bn * 256 + r1) * rowK + kbase + c1 * 16;
  const size_t hst = (size_t)128 * rowK;

  enum { A0S = 0, A1S = 16384, A2S = 32768, A3S = 49152,
         B0S = 65536, B1S = 81920, B2S = 98304, B3S = 114688 };

#define STG(slot, pa, pb, off) do { \
    gload_lds16((pa) + (off), lds + (slot) + wid * 1024); \
    gload_lds16((pb) + (off), lds + (slot) + 8192 + wid * 1024); } while (0)

  const bf16_t* Ae = (const bf16_t*)(lds + A0S + wr * 16384);
  const bf16_t* Be = (const bf16_t*)(lds + B0S + (wc >> 1) * 16384);
  const bf16_t* Ao = (const bf16_t*)(lds + A2S + wr * 16384);
  const bf16_t* Bo = (const bf16_t*)(lds + B2S + (wc >> 1) * 16384);
  const int bro = (wc & 1) * 64;

  f32x4 acc[8][4] = {};
  bf16x8 a[4][2], b[4][2];
  const int xr = l15 & 7;
  const int ck0 = (lhi ^ xr) * 8;
  const int ck1 = ((4 + lhi) ^ xr) * 8;

#define RD_A(base, rb) do { _Pragma("unroll") \
    for (int mi = 0; mi < 4; ++mi) { \
      const int ro = ((rb) + mi * 16 + l15) * 64; \
      a[mi][0] = *(const bf16x8*)((base) + ro + ck0); \
      a[mi][1] = *(const bf16x8*)((base) + ro + ck1); } } while (0)
#define RD_B(base) do { _Pragma("unroll") \
    for (int n = 0; n < 4; ++n) { \
      const int ro = (bro + n * 16 + l15) * 64; \
      b[n][0] = *(const bf16x8*)((base) + ro + ck0); \
      b[n][1] = *(const bf16x8*)((base) + ro + ck1); } } while (0)
#define MM(qm, qn) do { _Pragma("unroll") \
    for (int mi = 0; mi < 4; ++mi) { _Pragma("unroll") \
      for (int ni = 0; ni < 2; ++ni) { \
        f32x4 t_ = acc[(qm) * 4 + mi][(qn) * 2 + ni]; \
        t_ = MFMA16(a[mi][0], b[(qn) * 2 + ni][0], t_); \
        t_ = MFMA16(a[mi][1], b[(qn) * 2 + ni][1], t_); \
        acc[(qm) * 4 + mi][(qn) * 2 + ni] = t_; } } } while (0)
#define PRIO_MM(qm, qn) do { __builtin_amdgcn_s_setprio(1); MM(qm, qn); \
    __builtin_amdgcn_s_setprio(0); } while (0)

  // prologue: tile0 (B0,B1,A0,A1 @ K-byte 0) + tile1 (B2,B3,A2 @ K-byte 128)
  STG(B0S, sB0, sB1, 0);
  STG(B1S, sB0, sB1, hst);
  STG(A0S, sA0, sA1, 0);
  STG(A1S, sA0, sA1, hst);
  STG(B2S, sB0, sB1, 128);
  STG(B3S, sB0, sB1, 128 + hst);
  STG(A2S, sA0, sA1, 128);
  asm volatile("s_waitcnt vmcnt(6)" ::: "memory");
  BARRIER();

  size_t g = 0;  // K-byte offset of the current even tile
  for (int ktp = 0; ktp < nkt / 2 - 1; ++ktp) {
    // ======== tile even (kt = 2*ktp, K-byte g; slots A0/A1, B0/B1) ========
    RD_A(Ae, 0); RD_B(Be);
    STG(A3S, sA0, sA1, g + 128 + hst);        // tile kt+1, A half1
    asm volatile("s_waitcnt lgkmcnt(8)" ::: "memory");
    BARRIER();
    PRIO_MM(0, 0);
    BARRIER();
    STG(B0S, sB0, sB1, g + 256);              // tile kt+2, B half0
    BARRIER();
    PRIO_MM(0, 1);
    BARRIER();
    RD_A(Ae, 64);
    STG(B1S, sB0, sB1, g + 256 + hst);        // tile kt+2, B half1
    BARRIER();
    PRIO_MM(1, 0);
    BARRIER();
    STG(A0S, sA0, sA1, g + 256);              // tile kt+2, A half0
    BARRIER();
    PRIO_MM(1, 1);
    asm volatile("s_waitcnt vmcnt(6)" ::: "memory");
    BARRIER();
    // ======== tile odd (kt+1, K-byte g+128; slots A2/A3, B2/B3) ========
    RD_A(Ao, 0); RD_B(Bo);
    STG(A1S, sA0, sA1, g + 256 + hst);        // tile kt+2, A half1
    asm volatile("s_waitcnt lgkmcnt(8)" ::: "memory");
    BARRIER();
    PRIO_MM(0, 0);
    BARRIER();
    STG(B2S, sB0, sB1, g + 384);              // tile kt+3, B half0
    BARRIER();
    PRIO_MM(0, 1);
    BARRIER();
    RD_A(Ao, 64);
    STG(B3S, sB0, sB1, g + 384 + hst);        // tile kt+3, B half1
    BARRIER();
    PRIO_MM(1, 0);
    BARRIER();
    STG(A2S, sA0, sA1, g + 384);              // tile kt+3, A half0
    BARRIER();
    PRIO_MM(1, 1);
    asm volatile("s_waitcnt vmcnt(6)" ::: "memory");
    BARRIER();
    g += 256;
  }
  // ======== tail tile nkt-2 (even, K-byte g) ========
  RD_A(Ae, 0); RD_B(Be);
  STG(A3S, sA0, sA1, g + 128 + hst);          // tile nkt-1, A half1
  BARRIER();
  PRIO_MM(0, 0);
  PRIO_MM(0, 1);
  RD_A(Ae, 64);
  PRIO_MM(1, 0);
  PRIO_MM(1, 1);
  asm volatile("s_waitcnt vmcnt(0)" ::: "memory");
  BARRIER();
  // ======== tail tile nkt-1 (odd) ========
  RD_A(Ao, 0); RD_B(Bo);
  PRIO_MM(0, 0);
  PRIO_MM(0, 1);
  RD_A(Ao, 64);
  PRIO_MM(1, 0);
  PRIO_MM(1, 1);

  // epilogue: write (partial) C
  CT* Cp = C + (size_t)ks * M * N;
#pragma unroll
  for (int m = 0; m < 8; ++m) {
    const int row0 = bm * 256 + wr * 128 + m * 16 + 4 * lhi;
#pragma unroll
    for (int n = 0; n < 4; ++n) {
      const int col = bn * 256 + wc * 64 + n * 16 + l15;
#pragma unroll
      for (int i = 0; i < 4; ++i)
        Cp[(size_t)(row0 + i) * N + col] = (CT)acc[m][n][i];
    }
  }
#undef STG
#undef RD_A
#undef RD_B
#undef MM
#undef PRIO_MM
}

// ---------------- RMSNorm + RoPE + bf16 pack of Q/K/V (sums split-K partials) ----------------
__global__ __launch_bounds__(256) void k_norm_rope(
    const bf16_t* __restrict__ qkvA, const bf16_t* __restrict__ qkvB,
    const int* __restrict__ pos,
    const float* __restrict__ qw, const float* __restrict__ kw,
    bf16_t* __restrict__ Q, bf16_t* __restrict__ Kk, bf16_t* __restrict__ V) {
  const int w = blockIdx.x * 4 + (threadIdx.x >> 6);
  const int lane = threadIdx.x & 63;
  const int n = w / 48, slot = w % 48;
  const bf16_t* rowA = qkvA + (size_t)n * 6144;
  const bf16_t* rowB = qkvB + (size_t)n * 6144;
  if (slot >= 40) {
    const int h2 = slot - 40;
    const int c = 5120 + h2 * 128 + lane;
    float x0 = (float)rowA[c] + (float)rowB[c];
    float x1 = (float)rowA[c + 64] + (float)rowB[c + 64];
    bf16_t* dst = V + ((size_t)n * 8 + h2) * 128;
    dst[lane] = (bf16_t)x0;
    dst[lane + 64] = (bf16_t)x1;
    return;
  }
  const bool isq = slot < 32;
  const int h = isq ? slot : slot - 32;
  const int coff = (isq ? h * 128 : 4096 + h * 128) + lane;
  float x0 = (float)rowA[coff] + (float)rowB[coff];
  float x1 = (float)rowA[coff + 64] + (float)rowB[coff + 64];
  float ss = x0 * x0 + x1 * x1;
#pragma unroll
  for (int m = 32; m; m >>= 1) ss += __shfl_xor(ss, m, 64);
  const float inv = rsqrtf(ss * (1.0f / 128.0f) + 1e-6f);
  const float* wgt = isq ? qw : kw;
  float y0 = x0 * inv * wgt[lane];
  float y1 = x1 * inv * wgt[lane + 64];
  const float ang = (float)pos[n] * expf((float)lane * -0.14391156608f);
  float sn, cs;
  sincosf(ang, &sn, &cs);
  float o0 = y0 * cs - y1 * sn;
  float o1 = y1 * cs + y0 * sn;
  bf16_t* dst = isq ? (Q + ((size_t)n * 32 + h) * 128) : (Kk + ((size_t)n * 8 + h) * 128);
  dst[lane] = (bf16_t)o0;
  dst[lane + 64] = (bf16_t)o1;
}

// ---------------- V transpose: V[4096][8][128] -> Vt[s][kvh][d][1024] ----------------
__global__ __launch_bounds__(256) void k_vt(const bf16_t* __restrict__ V,
                                            bf16_t* __restrict__ Vt) {
  __shared__ bf16_t T[64][136];
  const int blk = blockIdx.x;              // 512 = s(4) x kvh(8) x tt(16)
  const int tt = blk & 15, kvh = (blk >> 4) & 7, s = blk >> 7;
  const int tok0 = tt * 64;
  const int tid = threadIdx.x;
#pragma unroll
  for (int k = 0; k < 4; ++k) {
    const int item = tid + k * 256;        // 0..1023
    const int tok = item >> 4, d0 = (item & 15) * 8;
    bf16x8 v = *(const bf16x8*)(V + ((size_t)(s * 1024 + tok0 + tok) * 8 + kvh) * 128 + d0);
    *(bf16x8*)(&T[tok][d0]) = v;
  }
  __syncthreads();
#pragma unroll
  for (int k = 0; k < 4; ++k) {
    const int item = tid + k * 256;
    const int d = item & 127, oct = item >> 7;
    bf16x8 o;
#pragma unroll
    for (int j = 0; j < 8; ++j) o[j] = T[oct * 8 + j][d];
    *(bf16x8*)(Vt + ((size_t)((s * 8 + kvh) * 128 + d)) * 1024 + tok0 + oct * 8) = o;
  }
}

// ---------------- causal GQA flash attention ----------------
// Block remap: x=b&7, y=b>>3; h=4x+((y>>3)&3) (one kv head per XCD);
// qb=7-(y&7); s=y>>5. K double-buffered in LDS (stage kt+1 overlaps tile kt's
// compute; single vmcnt(0)+barrier per tile). V read directly from pre-transposed
// global Vt (L2-resident per XCD). P bounced through per-wave LDS (no barrier).
__global__ __launch_bounds__(256, 2) void k_attn(
    const bf16_t* __restrict__ Q, const bf16_t* __restrict__ Kk,
    const bf16_t* __restrict__ Vt, bf16_t* __restrict__ O) {
  __shared__ __align__(16) bf16_t Ks[2][64 * 128];   // 2 x 16 KB, XOR-swizzled
  __shared__ __align__(16) bf16_t Ps[4][32 * 72];
  const int b = blockIdx.x;
  const int x = b & 7, y = b >> 3;
  const int h = x * 4 + ((y >> 3) & 3);
  const int qb = 7 - (y & 7);
  const int s = y >> 5;
  const int kvh = h >> 2;
  const int tid = threadIdx.x, lane = tid & 63, wid = tid >> 6;
  const int l15 = lane & 15, lhi = lane >> 4;

  // hoist Q fragments
  bf16x8 qf[2][4];
  {
    const int qrow = qb * 128 + wid * 32;
#pragma unroll
    for (int mt = 0; mt < 2; mt++) {
      const size_t base = ((size_t)(s * 1024 + qrow + mt * 16 + l15) * 32 + h) * 128;
#pragma unroll
      for (int kc = 0; kc < 4; kc++)
        qf[mt][kc] = *(const bf16x8*)(Q + base + kc * 32 + 8 * lhi);
    }
  }
  const bf16_t* Vtb = Vt + (size_t)((s * 8 + kvh) * 128) * 1024;  // [d][1024 tokens]

  f32x4 of[2][8] = {};
  float mx[2][4], li[2][4];
#pragma unroll
  for (int mt = 0; mt < 2; mt++)
#pragma unroll
    for (int i = 0; i < 4; i++) { mx[mt][i] = -1e30f; li[mt][i] = 0.f; }

  const int ktiles = (qb + 1) * 2;

  // K staging: wave stages 4 KB; pre-swizzled source, linear LDS dest
  const int so = wid * 4096;  // wave's byte base within tile
#define STAGE_K(kt_, buf_) do { _Pragma("unroll") \
    for (int c = 0; c < 4; ++c) { \
      const int o = so + c * 1024 + lane * 16; \
      const int krow = o >> 8; \
      const int cs = ((o >> 4) & 15) ^ (krow & 7); \
      const char* src = (const char*)(Kk + \
          ((size_t)(s * 1024 + (kt_) * 64 + krow) * 8 + kvh) * 128) + cs * 16; \
      gload_lds16(src, (char*)&Ks[buf_][0] + so + c * 1024); \
    } } while (0)

  STAGE_K(0, 0);
  asm volatile("s_waitcnt vmcnt(0)" ::: "memory");
  BARRIER();

  for (int kt = 0; kt < ktiles; kt++) {
    const int kv0 = kt * 64;
    const int buf = kt & 1;
    if (kt + 1 < ktiles) STAGE_K(kt + 1, buf ^ 1);

    // QK^T : S[32 q][64 kv] from LDS K
    f32x4 sf[2][4] = {};
#pragma unroll
    for (int kc = 0; kc < 4; kc++) {
      bf16x8 kf[4];
#pragma unroll
      for (int n = 0; n < 4; n++) {
        const int krow = n * 16 + l15;
        const int ci = (kc * 4 + lhi) ^ (krow & 7);
        kf[n] = *(const bf16x8*)(&Ks[buf][0] + krow * 128 + ci * 8);
      }
#pragma unroll
      for (int mt = 0; mt < 2; mt++)
#pragma unroll
        for (int n = 0; n < 4; n++)
          sf[mt][n] = MFMA16(qf[mt][kc], kf[n], sf[mt][n]);
    }

    // online softmax
    const bool masked = (kt >= 2 * qb);
    const float scale = 0.08838834764831845f;
    float pv[2][4][4];
#pragma unroll
    for (int mt = 0; mt < 2; mt++) {
#pragma unroll
      for (int i = 0; i < 4; i++) {
        float rm = -1e30f;
#pragma unroll
        for (int n = 0; n < 4; n++) {
          float sv = sf[mt][n][i] * scale;
          if (masked) {
            const int kvg = kv0 + n * 16 + l15;
            const int qg = qb * 128 + wid * 32 + mt * 16 + 4 * lhi + i;
            if (kvg > qg) sv = -1e30f;
          }
          pv[mt][n][i] = sv;
          rm = fmaxf(rm, sv);
        }
#pragma unroll
        for (int mm = 1; mm < 16; mm <<= 1) rm = fmaxf(rm, __shfl_xor(rm, mm, 64));
        const float nm = fmaxf(mx[mt][i], rm);
        float ts = 0.f;
#pragma unroll
        for (int n = 0; n < 4; n++) {
          float e = __expf(pv[mt][n][i] - nm);
          pv[mt][n][i] = e;
          ts += e;
        }
#pragma unroll
        for (int mm = 1; mm < 16; mm <<= 1) ts += __shfl_xor(ts, mm, 64);
        const float al = __expf(mx[mt][i] - nm);
        li[mt][i] = li[mt][i] * al + ts;
        mx[mt][i] = nm;
#pragma unroll
        for (int n = 0; n < 8; n++) of[mt][n][i] *= al;
      }
    }

    // P -> per-wave LDS bounce (A-operand re-layout); same-wave, no barrier
    bf16_t* myP = &Ps[wid][0];
#pragma unroll
    for (int mt = 0; mt < 2; mt++)
#pragma unroll
      for (int n = 0; n < 4; n++)
#pragma unroll
        for (int i = 0; i < 4; i++)
          myP[(mt * 16 + 4 * lhi + i) * 72 + n * 16 + l15] = (bf16_t)pv[mt][n][i];

    // PV : O[32 q][128 d] += P[32][64] * V[64][128]; V from global Vt (L2)
#pragma unroll
    for (int kc = 0; kc < 2; kc++) {
      bf16x8 pf[2];
#pragma unroll
      for (int mt = 0; mt < 2; mt++)
        pf[mt] = *(const bf16x8*)(myP + (mt * 16 + l15) * 72 + kc * 32 + 8 * lhi);
#pragma unroll
      for (int n = 0; n < 8; n++) {
        const int d = n * 16 + l15;
        bf16x8 vf = *(const bf16x8*)(Vtb + (size_t)d * 1024 + kv0 + kc * 32 + 8 * lhi);
#pragma unroll
        for (int mt = 0; mt < 2; mt++)
          of[mt][n] = MFMA16(pf[mt], vf, of[mt][n]);
      }
    }

    if (kt + 1 < ktiles) {
      asm volatile("s_waitcnt vmcnt(0)" ::: "memory");
      BARRIER();
    }
  }
#undef STAGE_K

  // epilogue: normalize + store bf16 O[token][h*128+d]
#pragma unroll
  for (int mt = 0; mt < 2; mt++) {
#pragma unroll
    for (int i = 0; i < 4; i++) {
      const float invl = 1.0f / li[mt][i];
      const int tokrow = qb * 128 + wid * 32 + mt * 16 + 4 * lhi + i;
      bf16_t* dst = O + (size_t)(s * 1024 + tokrow) * 4096 + h * 128;
#pragma unroll
      for (int n = 0; n < 8; n++)
        dst[n * 16 + l15] = (bf16_t)(of[mt][n][i] * invl);
    }
  }
}

// ---------------- launch ----------------
extern "C" void kernel_launch(void* const* d_in, const int* in_sizes, int n_in,
                              void* d_out, int out_size, void* d_ws, size_t ws_size,
                              hipStream_t stream) {
  const float* hidden = (const float*)d_in[0];
  const float* mu     = (const float*)d_in[1];
  const int*   pos    = (const int*)d_in[2];
  const float* Wq  = (const float*)d_in[3];
  const float* Wk  = (const float*)d_in[4];
  const float* Wv  = (const float*)d_in[5];
  const float* Wo  = (const float*)d_in[6];
  const float* Wmq = (const float*)d_in[7];
  const float* Wmk = (const float*)d_in[8];
  const float* Wmv = (const float*)d_in[9];
  const float* qw  = (const float*)d_in[10];
  const float* kw  = (const float*)d_in[11];
  float* out = (float*)d_out;
  char* ws = (char*)d_ws;

  if (ws_size < 301989888u) return;  // need 288 MiB

  bf16_t* Wqkv = (bf16_t*)(ws);                    // [6144][8192] bf16   0..96MiB
  bf16_t* Wob  = (bf16_t*)(ws + 100663296);        // [4096][4096] bf16   96..128MiB
  bf16_t* Xb   = (bf16_t*)(ws + 134217728);        // [4096][8192] bf16   128..192MiB
  bf16_t* Qb   = (bf16_t*)(ws + 134217728);        // aliases Xb (dead after GEMM1) 32MiB
  bf16_t* Kb   = (bf16_t*)(ws + 167772160);        // 8MiB
  bf16_t* Vb   = (bf16_t*)(ws + 176160768);        // 8MiB
  bf16_t* VtG  = (bf16_t*)(ws + 184549376);        // transposed V, 8MiB
  bf16_t* qkvA = (bf16_t*)(ws + 201326592);        // [4096][6144] bf16 partial ks=0 (48MiB)
  bf16_t* qkvB = (bf16_t*)(ws + 251658240);        // partial ks=1 (48MiB)
  bf16_t* Ob   = (bf16_t*)(ws + 201326592);        // aliases qkvA (dead after norm/rope) 32MiB

  k_pack_all<<<2048, 256, 0, stream>>>(hidden, mu, Wq, Wmq, Wk, Wmk, Wv, Wmv, Wo,
                                       Xb, Wqkv, Wob);
  k_gemm256<bf16_t, 2><<<768, 512, 0, stream>>>(Xb, Wqkv, qkvA, 4096, 6144, 8192);
  k_norm_rope<<<49152, 256, 0, stream>>>(qkvA, qkvB, pos, qw, kw, Qb, Kb, Vb);
  k_vt<<<512, 256, 0, stream>>>(Vb, VtG);
  k_attn<<<1024, 256, 0, stream>>>(Qb, Kb, VtG, Ob);
  k_gemm256<float, 1><<<256, 512, 0, stream>>>(Ob, Wob, out, 4096, 4096, 4096);
}